// Round 1
// baseline (1591.189 us; speedup 1.0000x reference)
//
#include <hip/hip_runtime.h>
#include <math.h>

#define NN 4096
#define HH 128
#define EE 65536
#define GG 64
#define NSPLIT 8
#define SPLITLEN (NN / NSPLIT)

// ---------------- input projection: h = [x, lap, rw] @ Wp + bp ----------------
__global__ __launch_bounds__(128) void input_proj_k(
    const float* __restrict__ x, const float* __restrict__ lap,
    const float* __restrict__ rw, const float* __restrict__ Wp,
    const float* __restrict__ bp, float* __restrict__ h) {
  int n = blockIdx.x, c = threadIdx.x;
  float acc = bp[c];
  #pragma unroll
  for (int k = 0; k < 64; k++) acc += x[n*64+k] * Wp[k*HH+c];
  #pragma unroll
  for (int k = 0; k < 8; k++)  acc += lap[n*8+k] * Wp[(64+k)*HH+c];
  #pragma unroll
  for (int k = 0; k < 16; k++) acc += rw[n*16+k] * Wp[(72+k)*HH+c];
  h[n*HH+c] = acc;
}

// ---------------- edge scatter-add: agg[dst] += h[src] ----------------
__global__ __launch_bounds__(256) void edge_agg_k(
    const int* __restrict__ ei, const float* __restrict__ h, float* agg) {
  int e = blockIdx.x*2 + (threadIdx.x >> 7);
  int c = threadIdx.x & 127;
  int s = ei[e], d = ei[EE + e];
  atomicAdd(&agg[d*HH+c], h[s*HH+c]);
}

// ---------------- generic GEMM: C = act((A(+A2)) @ B + bias) ----------------
template <int K>
__global__ __launch_bounds__(256) void gemm_k(
    const float* __restrict__ A, const float* __restrict__ A2,
    const float* __restrict__ B, const float* __restrict__ bias,
    float* __restrict__ C, int Nr, int M, int act) {
  int idx = blockIdx.x*256 + threadIdx.x;
  if (idx >= Nr*M) return;
  int n = idx / M, mm = idx - n*M;
  float acc = bias[mm];
  if (A2) {
    #pragma unroll 8
    for (int k = 0; k < K; k++) acc += (A[n*K+k] + A2[n*K+k]) * B[k*M+mm];
  } else {
    #pragma unroll 8
    for (int k = 0; k < K; k++) acc += A[n*K+k] * B[k*M+mm];
  }
  C[idx] = act ? fmaxf(acc, 0.f) : acc;
}

// ---------------- BN: per-channel sum / sumsq over (x1+x2+x3) ----------------
__global__ __launch_bounds__(256) void bn_stats_k(
    const float* __restrict__ x1, const float* __restrict__ x2,
    const float* __restrict__ x3, float* stats) {
  __shared__ float ss[256], sq[256];
  int c = threadIdx.x & 127, half = threadIdx.x >> 7;
  float s = 0.f, q = 0.f;
  int base = blockIdx.x * 64;
  for (int n = base + half; n < base + 64; n += 2) {
    float v = x1[n*HH+c];
    if (x2) v += x2[n*HH+c];
    if (x3) v += x3[n*HH+c];
    s += v; q += v*v;
  }
  ss[threadIdx.x] = s; sq[threadIdx.x] = q;
  __syncthreads();
  if (threadIdx.x < 128) {
    atomicAdd(&stats[c],       ss[threadIdx.x] + ss[threadIdx.x+128]);
    atomicAdd(&stats[128+c],   sq[threadIdx.x] + sq[threadIdx.x+128]);
  }
}

__global__ __launch_bounds__(256) void bn_apply_k(
    const float* __restrict__ x1, const float* __restrict__ x2,
    const float* __restrict__ x3, const float* __restrict__ stats,
    const float* __restrict__ gamma, const float* __restrict__ beta,
    float* __restrict__ y, int act) {
  int idx = blockIdx.x*256 + threadIdx.x;
  int c = idx & 127;
  float mean = stats[c] * (1.f/NN);
  float var  = stats[128+c] * (1.f/NN) - mean*mean;
  float rs = rsqrtf(var + 1e-5f);
  float v = x1[idx];
  if (x2) v += x2[idx];
  if (x3) v += x3[idx];
  float r = (v - mean) * rs * gamma[c] + beta[c];
  y[idx] = act ? fmaxf(r, 0.f) : r;
}

// ---------------- flash attention (fp32, online softmax, key-split) ----------------
// grid: (NSPLIT, NN/256, 4 heads), block 256. One query per thread.
__global__ __launch_bounds__(256) void flash_attn_k(
    const float* __restrict__ qkv, float* __restrict__ opart,
    float* __restrict__ mlpart) {
  const int split = blockIdx.x;
  const int head  = blockIdx.z;
  const int qi    = blockIdx.y*256 + threadIdx.x;
  const float scale = 0.17677669529663687f;  // 1/sqrt(32)

  float q[32];
  {
    const float4* q4 = reinterpret_cast<const float4*>(qkv + (size_t)qi*384 + head*32);
    #pragma unroll
    for (int i = 0; i < 8; i++) {
      float4 t = q4[i];
      q[4*i+0]=t.x; q[4*i+1]=t.y; q[4*i+2]=t.z; q[4*i+3]=t.w;
    }
  }
  float o[32];
  #pragma unroll
  for (int d = 0; d < 32; d++) o[d] = 0.f;
  float m = -1e30f, l = 0.f;

  const int j0 = split*SPLITLEN, j1 = j0 + SPLITLEN;
  for (int jt = j0; jt < j1; jt += 16) {
    float s[16];
    #pragma unroll
    for (int jj = 0; jj < 16; jj++) {
      // wave-uniform address -> scalar-load candidate
      const float4* k4 = reinterpret_cast<const float4*>(qkv + (size_t)(jt+jj)*384 + 128 + head*32);
      float acc = 0.f;
      #pragma unroll
      for (int i = 0; i < 8; i++) {
        float4 t = k4[i];
        acc += q[4*i+0]*t.x + q[4*i+1]*t.y + q[4*i+2]*t.z + q[4*i+3]*t.w;
      }
      s[jj] = acc * scale;
    }
    float tm = s[0];
    #pragma unroll
    for (int jj = 1; jj < 16; jj++) tm = fmaxf(tm, s[jj]);
    float mn = fmaxf(m, tm);
    float corr = __expf(m - mn);
    m = mn; l *= corr;
    #pragma unroll
    for (int d = 0; d < 32; d++) o[d] *= corr;
    #pragma unroll
    for (int jj = 0; jj < 16; jj++) {
      float p = __expf(s[jj] - m);
      l += p;
      const float4* v4 = reinterpret_cast<const float4*>(qkv + (size_t)(jt+jj)*384 + 256 + head*32);
      #pragma unroll
      for (int i = 0; i < 8; i++) {
        float4 t = v4[i];
        o[4*i+0] += p*t.x; o[4*i+1] += p*t.y; o[4*i+2] += p*t.z; o[4*i+3] += p*t.w;
      }
    }
  }
  size_t b = (size_t)(split*4 + head)*NN + qi;
  float4* op4 = reinterpret_cast<float4*>(opart + b*32);
  #pragma unroll
  for (int i = 0; i < 8; i++)
    op4[i] = make_float4(o[4*i+0], o[4*i+1], o[4*i+2], o[4*i+3]);
  mlpart[b*2+0] = m;
  mlpart[b*2+1] = l;
}

// combine NSPLIT partials -> attno[n, head*32+d]
__global__ __launch_bounds__(256) void attn_merge_k(
    const float* __restrict__ opart, const float* __restrict__ mlpart,
    float* __restrict__ attno) {
  int idx = blockIdx.x*256 + threadIdx.x;   // heads*N*32
  int d = idx & 31;
  int n = (idx >> 5) & (NN-1);
  int head = idx >> 17;
  float M = -1e30f;
  #pragma unroll
  for (int s = 0; s < NSPLIT; s++)
    M = fmaxf(M, mlpart[((size_t)(s*4+head)*NN + n)*2]);
  float L = 0.f, O = 0.f;
  #pragma unroll
  for (int s = 0; s < NSPLIT; s++) {
    size_t b = (size_t)(s*4+head)*NN + n;
    float w = __expf(mlpart[b*2] - M);
    L += mlpart[b*2+1] * w;
    O += opart[b*32 + d] * w;
  }
  attno[n*HH + head*32 + d] = O / L;
}

// ---------------- global add pool ----------------
__global__ __launch_bounds__(256) void pool_k(
    const float* __restrict__ h, const int* __restrict__ batch, float* pooled) {
  int n = blockIdx.x*2 + (threadIdx.x >> 7);
  int c = threadIdx.x & 127;
  atomicAdd(&pooled[batch[n]*HH+c], h[n*HH+c]);
}

extern "C" void kernel_launch(void* const* d_in, const int* in_sizes, int n_in,
                              void* d_out, int out_size, void* d_ws, size_t ws_size,
                              hipStream_t stream) {
  const float* x      = (const float*)d_in[0];
  const float* lap    = (const float*)d_in[1];
  const float* rw     = (const float*)d_in[2];
  const int*   ei     = (const int*)d_in[3];
  const int*   batch  = (const int*)d_in[4];
  const float* Wp     = (const float*)d_in[5];
  const float* bp     = (const float*)d_in[6];
  const float* gin_W1 = (const float*)d_in[7];
  const float* gin_b1 = (const float*)d_in[8];
  const float* gin_W2 = (const float*)d_in[9];
  const float* gin_b2 = (const float*)d_in[10];
  const float* bn1_g  = (const float*)d_in[11];
  const float* bn1_b  = (const float*)d_in[12];
  const float* bn2_g  = (const float*)d_in[13];
  const float* bn2_b  = (const float*)d_in[14];
  const float* bn3_g  = (const float*)d_in[15];
  const float* bn3_b  = (const float*)d_in[16];
  const float* ain_w  = (const float*)d_in[17];
  const float* ain_b  = (const float*)d_in[18];
  const float* aout_w = (const float*)d_in[19];
  const float* aout_b = (const float*)d_in[20];
  const float* mlp_W1 = (const float*)d_in[21];
  const float* mlp_b1 = (const float*)d_in[22];
  const float* mlp_W2 = (const float*)d_in[23];
  const float* mlp_b2 = (const float*)d_in[24];
  const float* Wr1    = (const float*)d_in[25];
  const float* br1    = (const float*)d_in[26];
  const float* Wr2    = (const float*)d_in[27];
  const float* br2    = (const float*)d_in[28];
  const float* Wc     = (const float*)d_in[29];
  const float* bc     = (const float*)d_in[30];
  float* out = (float*)d_out;

  float* w = (float*)d_ws;
  float* h      = w + 0;          // 524288
  float* agg    = w + 524288;     // 524288
  float* gtmp   = w + 1048576;    // 524288
  float* gbuf   = w + 1572864;    // 524288
  float* qkv    = w + 2097152;    // 1572864
  float* attno  = w + 3670016;    // 524288
  float* obuf   = w + 4194304;    // 524288
  float* mlph   = w + 4718592;    // 1048576
  float* mbuf   = w + 5767168;    // 524288
  float* opart  = w + 6291456;    // 4194304
  float* mlpart = w + 10485760;   // 262144
  float* stats  = w + 10747904;   // 256
  float* pooled = w + 10748160;   // 8192
  float* r1     = w + 10756352;   // 8192
  float* r2     = w + 10764544;   // 8192

  input_proj_k<<<NN, 128, 0, stream>>>(x, lap, rw, Wp, bp, h);

  for (int l = 0; l < 2; l++) {
    // ---- GIN branch ----
    hipMemsetAsync(agg, 0, (size_t)NN*HH*sizeof(float), stream);
    edge_agg_k<<<EE/2, 256, 0, stream>>>(ei, h, agg);
    gemm_k<128><<<(NN*HH+255)/256, 256, 0, stream>>>(h, agg, gin_W1 + l*HH*HH, gin_b1 + l*HH, gtmp, NN, HH, 1);
    gemm_k<128><<<(NN*HH+255)/256, 256, 0, stream>>>(gtmp, nullptr, gin_W2 + l*HH*HH, gin_b2 + l*HH, mbuf, NN, HH, 0);
    hipMemsetAsync(stats, 0, 256*sizeof(float), stream);
    bn_stats_k<<<64, 256, 0, stream>>>(mbuf, h, nullptr, stats);
    bn_apply_k<<<NN*HH/256, 256, 0, stream>>>(mbuf, h, nullptr, stats, bn1_g + l*HH, bn1_b + l*HH, gbuf, 0);

    // ---- attention branch ----
    gemm_k<128><<<(NN*384+255)/256, 256, 0, stream>>>(h, nullptr, ain_w + l*HH*384, ain_b + l*384, qkv, NN, 384, 0);
    dim3 fgrid(NSPLIT, NN/256, 4);
    flash_attn_k<<<fgrid, 256, 0, stream>>>(qkv, opart, mlpart);
    attn_merge_k<<<(4*NN*32)/256, 256, 0, stream>>>(opart, mlpart, attno);
    gemm_k<128><<<(NN*HH+255)/256, 256, 0, stream>>>(attno, nullptr, aout_w + l*HH*HH, aout_b + l*HH, gtmp, NN, HH, 0);
    hipMemsetAsync(stats, 0, 256*sizeof(float), stream);
    bn_stats_k<<<64, 256, 0, stream>>>(gtmp, h, nullptr, stats);
    bn_apply_k<<<NN*HH/256, 256, 0, stream>>>(gtmp, h, nullptr, stats, bn2_g + l*HH, bn2_b + l*HH, obuf, 0);

    // ---- combine + FFN ----
    gemm_k<128><<<(NN*256+255)/256, 256, 0, stream>>>(gbuf, obuf, mlp_W1 + l*HH*256, mlp_b1 + l*256, mlph, NN, 256, 1);
    gemm_k<256><<<(NN*HH+255)/256, 256, 0, stream>>>(mlph, nullptr, mlp_W2 + l*256*HH, mlp_b2 + l*HH, mbuf, NN, HH, 0);
    hipMemsetAsync(stats, 0, 256*sizeof(float), stream);
    bn_stats_k<<<64, 256, 0, stream>>>(gbuf, obuf, mbuf, stats);
    bn_apply_k<<<NN*HH/256, 256, 0, stream>>>(gbuf, obuf, mbuf, stats, bn3_g + l*HH, bn3_b + l*HH, h, 1);
  }

  // ---- pool + head MLP ----
  hipMemsetAsync(pooled, 0, (size_t)GG*HH*sizeof(float), stream);
  pool_k<<<NN/2, 256, 0, stream>>>(h, batch, pooled);
  gemm_k<128><<<(GG*HH+255)/256, 256, 0, stream>>>(pooled, nullptr, Wr1, br1, r1, GG, HH, 1);
  gemm_k<128><<<(GG*HH+255)/256, 256, 0, stream>>>(r1, nullptr, Wr2, br2, r2, GG, HH, 1);
  gemm_k<128><<<(GG*10+255)/256, 256, 0, stream>>>(r2, nullptr, Wc, bc, out, GG, 10, 0);
}

// Round 2
// 713.233 us; speedup vs baseline: 2.2310x; 2.2310x over previous
//
#include <hip/hip_runtime.h>
#include <math.h>

#define NN 4096
#define HH 128
#define EE 65536
#define GG 64
#define KSPLIT 4
#define KLEN (NN / KSPLIT)

typedef unsigned short u16;
typedef unsigned int u32;
typedef __bf16 bf16x8 __attribute__((ext_vector_type(8)));
typedef float f32x4 __attribute__((ext_vector_type(4)));

__device__ inline u16 f2b(float f) {
  u32 u = __float_as_uint(f);
  u += 0x7FFFu + ((u >> 16) & 1u);
  return (u16)(u >> 16);
}

// ---------------- input projection: h = [x, lap, rw] @ Wp + bp ----------------
__global__ __launch_bounds__(128) void input_proj_k(
    const float* __restrict__ x, const float* __restrict__ lap,
    const float* __restrict__ rw, const float* __restrict__ Wp,
    const float* __restrict__ bp, float* __restrict__ h) {
  int n = blockIdx.x, c = threadIdx.x;
  float acc = bp[c];
  #pragma unroll
  for (int k = 0; k < 64; k++) acc += x[n*64+k] * Wp[k*HH+c];
  #pragma unroll
  for (int k = 0; k < 8; k++)  acc += lap[n*8+k] * Wp[(64+k)*HH+c];
  #pragma unroll
  for (int k = 0; k < 16; k++) acc += rw[n*16+k] * Wp[(72+k)*HH+c];
  h[n*HH+c] = acc;
}

// ---------------- edge scatter-add: agg[dst] += h[src] ----------------
__global__ __launch_bounds__(256) void edge_agg_k(
    const int* __restrict__ ei, const float* __restrict__ h, float* agg) {
  int e = blockIdx.x*2 + (threadIdx.x >> 7);
  int c = threadIdx.x & 127;
  int s = ei[e], d = ei[EE + e];
  atomicAdd(&agg[d*HH+c], h[s*HH+c]);
}

// ---------------- generic GEMM: C = act((A(+A2)) @ B + bias) ----------------
template <int K>
__global__ __launch_bounds__(256) void gemm_k(
    const float* __restrict__ A, const float* __restrict__ A2,
    const float* __restrict__ B, const float* __restrict__ bias,
    float* __restrict__ C, int Nr, int M, int act) {
  int idx = blockIdx.x*256 + threadIdx.x;
  if (idx >= Nr*M) return;
  int n = idx / M, mm = idx - n*M;
  float acc = bias[mm];
  if (A2) {
    #pragma unroll 8
    for (int k = 0; k < K; k++) acc += (A[n*K+k] + A2[n*K+k]) * B[k*M+mm];
  } else {
    #pragma unroll 8
    for (int k = 0; k < K; k++) acc += A[n*K+k] * B[k*M+mm];
  }
  C[idx] = act ? fmaxf(acc, 0.f) : acc;
}

// ---------------- BN: per-channel sum / sumsq over (x1+x2+x3) ----------------
__global__ __launch_bounds__(256) void bn_stats_k(
    const float* __restrict__ x1, const float* __restrict__ x2,
    const float* __restrict__ x3, float* stats) {
  __shared__ float ss[256], sq[256];
  int c = threadIdx.x & 127, half = threadIdx.x >> 7;
  float s = 0.f, q = 0.f;
  int base = blockIdx.x * 64;
  for (int n = base + half; n < base + 64; n += 2) {
    float v = x1[n*HH+c];
    if (x2) v += x2[n*HH+c];
    if (x3) v += x3[n*HH+c];
    s += v; q += v*v;
  }
  ss[threadIdx.x] = s; sq[threadIdx.x] = q;
  __syncthreads();
  if (threadIdx.x < 128) {
    atomicAdd(&stats[c],       ss[threadIdx.x] + ss[threadIdx.x+128]);
    atomicAdd(&stats[128+c],   sq[threadIdx.x] + sq[threadIdx.x+128]);
  }
}

__global__ __launch_bounds__(256) void bn_apply_k(
    const float* __restrict__ x1, const float* __restrict__ x2,
    const float* __restrict__ x3, const float* __restrict__ stats,
    const float* __restrict__ gamma, const float* __restrict__ beta,
    float* __restrict__ y, int act) {
  int idx = blockIdx.x*256 + threadIdx.x;
  int c = idx & 127;
  float mean = stats[c] * (1.f/NN);
  float var  = stats[128+c] * (1.f/NN) - mean*mean;
  float rs = rsqrtf(var + 1e-5f);
  float v = x1[idx];
  if (x2) v += x2[idx];
  if (x3) v += x3[idx];
  float r = (v - mean) * rs * gamma[c] + beta[c];
  y[idx] = act ? fmaxf(r, 0.f) : r;
}

// ---------------- qkv fp32 -> bf16 conversion ----------------
// qb[head][n][d] = bf16(q * scale * log2e);  kb[head][n][d] = bf16(k)
__global__ __launch_bounds__(256) void conv_qk_k(
    const float* __restrict__ qkv, u16* __restrict__ qb, u16* __restrict__ kb) {
  const float QS = 0.17677669529663687f * 1.4426950408889634f;
  int idx = blockIdx.x*256 + threadIdx.x;       // 4096*256
  int n = idx >> 8, c = idx & 255;
  int head = (c & 127) >> 5, d = c & 31;
  float v = qkv[(size_t)n*384 + c];
  size_t o = ((size_t)(head*NN) + n)*32 + d;
  if (c < 128) qb[o] = f2b(v * QS);
  else         kb[o] = f2b(v);
}

// vt[c][n] = bf16(v[n][c])  (c = head*32+d), via LDS tile transpose
__global__ __launch_bounds__(256) void conv_v_k(
    const float* __restrict__ qkv, u16* __restrict__ vt) {
  __shared__ u16 lds[128][72];
  int n0 = blockIdx.x * 64;
  for (int e = threadIdx.x; e < 64*128; e += 256) {
    int r = e >> 7, c = e & 127;
    lds[c][r] = f2b(qkv[(size_t)(n0 + r)*384 + 256 + c]);
  }
  __syncthreads();
  int c = threadIdx.x >> 1, half = threadIdx.x & 1;
  uint4* dst = reinterpret_cast<uint4*>(vt + (size_t)c*NN + n0 + half*32);
  const uint4* src = reinterpret_cast<const uint4*>(&lds[c][half*32]);
  dst[0] = src[0]; dst[1] = src[1];
}

// ---------------- MFMA flash attention ----------------
// grid (KSPLIT, NN/64, 4 heads), block 256 (4 waves, 16 queries each).
// S^T = mfma(K, Q): lane holds query col li=lane&15, keys 4g+r per 16-key tile.
__global__ __launch_bounds__(256) void mfma_attn_k(
    const u16* __restrict__ qb, const u16* __restrict__ kb,
    const u16* __restrict__ vt, float* __restrict__ opart,
    float* __restrict__ mlpart) {
  __shared__ u16 pbuf[4][16*72];     // per-wave P [16 rows][64 cols, stride 72]
  __shared__ float corrbuf[4][16];

  const int w = threadIdx.x >> 6, lane = threadIdx.x & 63;
  const int g = lane >> 4, li = lane & 15;
  const int head = blockIdx.z;
  const int q0 = blockIdx.y * 64 + w * 16;
  const int j0 = blockIdx.x * KLEN;

  const bf16x8 qf = *reinterpret_cast<const bf16x8*>(
      qb + ((size_t)(head*NN) + q0 + li)*32 + g*8);

  f32x4 oacc0 = {0.f,0.f,0.f,0.f}, oacc1 = {0.f,0.f,0.f,0.f};
  const f32x4 zz = {0.f,0.f,0.f,0.f};
  float m = -1e30f, lsum = 0.f;
  u16* prow = &pbuf[w][li*72];

  for (int jt = j0; jt < j0 + KLEN; jt += 64) {
    f32x4 st[4];
    #pragma unroll
    for (int t = 0; t < 4; t++) {
      bf16x8 kf = *reinterpret_cast<const bf16x8*>(
          kb + ((size_t)(head*NN) + jt + t*16 + li)*32 + g*8);
      st[t] = __builtin_amdgcn_mfma_f32_16x16x32_bf16(kf, qf, zz, 0, 0, 0);
    }
    // running max across this 64-key block (lanes li,li+16,li+32,li+48 share query li)
    float tm = st[0][0];
    #pragma unroll
    for (int t = 0; t < 4; t++)
      #pragma unroll
      for (int r = 0; r < 4; r++) tm = fmaxf(tm, st[t][r]);
    tm = fmaxf(tm, __shfl_xor(tm, 16));
    tm = fmaxf(tm, __shfl_xor(tm, 32));
    float mnew = fmaxf(m, tm);
    float corr = exp2f(m - mnew);
    m = mnew;
    lsum *= corr;
    // p = exp2(s - m), accumulate partial row-sum, pack to bf16, stash in LDS
    #pragma unroll
    for (int t = 0; t < 4; t++) {
      float p0 = exp2f(st[t][0] - m), p1 = exp2f(st[t][1] - m);
      float p2 = exp2f(st[t][2] - m), p3 = exp2f(st[t][3] - m);
      lsum += p0 + p1 + p2 + p3;
      uint2 wv;
      wv.x = (u32)f2b(p0) | ((u32)f2b(p1) << 16);
      wv.y = (u32)f2b(p2) | ((u32)f2b(p3) << 16);
      *reinterpret_cast<uint2*>(prow + t*16 + g*4) = wv;
    }
    if (lane < 16) corrbuf[w][lane] = corr;
    f32x4 cv = *reinterpret_cast<f32x4*>(&corrbuf[w][g*4]);
    #pragma unroll
    for (int r = 0; r < 4; r++) { oacc0[r] *= cv[r]; oacc1[r] *= cv[r]; }
    // PV: two 32-key chunks, two 16-wide d halves
    #pragma unroll
    for (int c = 0; c < 2; c++) {
      bf16x8 pa = *reinterpret_cast<const bf16x8*>(&pbuf[w][li*72 + c*32 + g*8]);
      const u16* vrow = vt + ((size_t)(head*32 + li))*NN + jt + c*32 + g*8;
      bf16x8 vb0 = *reinterpret_cast<const bf16x8*>(vrow);
      bf16x8 vb1 = *reinterpret_cast<const bf16x8*>(vrow + (size_t)16*NN);
      oacc0 = __builtin_amdgcn_mfma_f32_16x16x32_bf16(pa, vb0, oacc0, 0, 0, 0);
      oacc1 = __builtin_amdgcn_mfma_f32_16x16x32_bf16(pa, vb1, oacc1, 0, 0, 0);
    }
  }
  // combine partial row-sums across the 4 lane groups
  lsum += __shfl_xor(lsum, 16);
  lsum += __shfl_xor(lsum, 32);

  size_t b = (size_t)(blockIdx.x*4 + head)*NN + q0;
  #pragma unroll
  for (int r = 0; r < 4; r++) {
    size_t ob = (b + 4*g + r)*32;
    opart[ob + li]      = oacc0[r];
    opart[ob + 16 + li] = oacc1[r];
  }
  if (lane < 16) {
    size_t bb = (b + lane)*2;
    mlpart[bb]   = m;
    mlpart[bb+1] = lsum;
  }
}

// combine KSPLIT partials -> attno[n, head*32+d]  (log2 domain)
__global__ __launch_bounds__(256) void attn_merge_k(
    const float* __restrict__ opart, const float* __restrict__ mlpart,
    float* __restrict__ attno) {
  int idx = blockIdx.x*256 + threadIdx.x;   // 4*NN*32
  int d = idx & 31;
  int n = (idx >> 5) & (NN-1);
  int head = idx >> 17;
  float M = -1e30f;
  #pragma unroll
  for (int s = 0; s < KSPLIT; s++)
    M = fmaxf(M, mlpart[((size_t)(s*4+head)*NN + n)*2]);
  float L = 0.f, O = 0.f;
  #pragma unroll
  for (int s = 0; s < KSPLIT; s++) {
    size_t b = (size_t)(s*4+head)*NN + n;
    float wgt = exp2f(mlpart[b*2] - M);
    L += mlpart[b*2+1] * wgt;
    O += opart[b*32 + d] * wgt;
  }
  attno[n*HH + head*32 + d] = O / L;
}

// ---------------- global add pool ----------------
__global__ __launch_bounds__(256) void pool_k(
    const float* __restrict__ h, const int* __restrict__ batch, float* pooled) {
  int n = blockIdx.x*2 + (threadIdx.x >> 7);
  int c = threadIdx.x & 127;
  atomicAdd(&pooled[batch[n]*HH+c], h[n*HH+c]);
}

extern "C" void kernel_launch(void* const* d_in, const int* in_sizes, int n_in,
                              void* d_out, int out_size, void* d_ws, size_t ws_size,
                              hipStream_t stream) {
  const float* x      = (const float*)d_in[0];
  const float* lap    = (const float*)d_in[1];
  const float* rw     = (const float*)d_in[2];
  const int*   ei     = (const int*)d_in[3];
  const int*   batch  = (const int*)d_in[4];
  const float* Wp     = (const float*)d_in[5];
  const float* bp     = (const float*)d_in[6];
  const float* gin_W1 = (const float*)d_in[7];
  const float* gin_b1 = (const float*)d_in[8];
  const float* gin_W2 = (const float*)d_in[9];
  const float* gin_b2 = (const float*)d_in[10];
  const float* bn1_g  = (const float*)d_in[11];
  const float* bn1_b  = (const float*)d_in[12];
  const float* bn2_g  = (const float*)d_in[13];
  const float* bn2_b  = (const float*)d_in[14];
  const float* bn3_g  = (const float*)d_in[15];
  const float* bn3_b  = (const float*)d_in[16];
  const float* ain_w  = (const float*)d_in[17];
  const float* ain_b  = (const float*)d_in[18];
  const float* aout_w = (const float*)d_in[19];
  const float* aout_b = (const float*)d_in[20];
  const float* mlp_W1 = (const float*)d_in[21];
  const float* mlp_b1 = (const float*)d_in[22];
  const float* mlp_W2 = (const float*)d_in[23];
  const float* mlp_b2 = (const float*)d_in[24];
  const float* Wr1    = (const float*)d_in[25];
  const float* br1    = (const float*)d_in[26];
  const float* Wr2    = (const float*)d_in[27];
  const float* br2    = (const float*)d_in[28];
  const float* Wc     = (const float*)d_in[29];
  const float* bc     = (const float*)d_in[30];
  float* out = (float*)d_out;

  float* w = (float*)d_ws;
  float* h      = w + 0;          // 524288
  float* agg    = w + 524288;     // 524288
  float* gtmp   = w + 1048576;    // 524288
  float* gbuf   = w + 1572864;    // 524288
  float* qkv    = w + 2097152;    // 1572864
  float* attno  = w + 3670016;    // 524288
  float* obuf   = w + 4194304;    // 524288
  float* mlph   = w + 4718592;    // 1048576
  float* mbuf   = w + 5767168;    // 524288
  float* opart  = w + 6291456;    // 2097152
  float* mlpart = w + 8388608;    // 131072
  float* stats  = w + 8519680;    // 256
  float* pooled = w + 8519936;    // 8192
  float* r1     = w + 8528128;    // 8192
  float* r2     = w + 8536320;    // 8192
  u16*   qb     = (u16*)(w + 8544512);  // 524288 u16
  u16*   kb     = (u16*)(w + 8806656);  // 524288 u16
  u16*   vt     = (u16*)(w + 9068800);  // 524288 u16

  input_proj_k<<<NN, 128, 0, stream>>>(x, lap, rw, Wp, bp, h);

  for (int l = 0; l < 2; l++) {
    // ---- GIN branch ----
    hipMemsetAsync(agg, 0, (size_t)NN*HH*sizeof(float), stream);
    edge_agg_k<<<EE/2, 256, 0, stream>>>(ei, h, agg);
    gemm_k<128><<<(NN*HH+255)/256, 256, 0, stream>>>(h, agg, gin_W1 + l*HH*HH, gin_b1 + l*HH, gtmp, NN, HH, 1);
    gemm_k<128><<<(NN*HH+255)/256, 256, 0, stream>>>(gtmp, nullptr, gin_W2 + l*HH*HH, gin_b2 + l*HH, mbuf, NN, HH, 0);
    hipMemsetAsync(stats, 0, 256*sizeof(float), stream);
    bn_stats_k<<<64, 256, 0, stream>>>(mbuf, h, nullptr, stats);
    bn_apply_k<<<NN*HH/256, 256, 0, stream>>>(mbuf, h, nullptr, stats, bn1_g + l*HH, bn1_b + l*HH, gbuf, 0);

    // ---- attention branch ----
    gemm_k<128><<<(NN*384+255)/256, 256, 0, stream>>>(h, nullptr, ain_w + l*HH*384, ain_b + l*384, qkv, NN, 384, 0);
    conv_qk_k<<<NN, 256, 0, stream>>>(qkv, qb, kb);
    conv_v_k<<<NN/64, 256, 0, stream>>>(qkv, vt);
    dim3 fgrid(KSPLIT, NN/64, 4);
    mfma_attn_k<<<fgrid, 256, 0, stream>>>(qb, kb, vt, opart, mlpart);
    attn_merge_k<<<(4*NN*32)/256, 256, 0, stream>>>(opart, mlpart, attno);
    gemm_k<128><<<(NN*HH+255)/256, 256, 0, stream>>>(attno, nullptr, aout_w + l*HH*HH, aout_b + l*HH, gtmp, NN, HH, 0);
    hipMemsetAsync(stats, 0, 256*sizeof(float), stream);
    bn_stats_k<<<64, 256, 0, stream>>>(gtmp, h, nullptr, stats);
    bn_apply_k<<<NN*HH/256, 256, 0, stream>>>(gtmp, h, nullptr, stats, bn2_g + l*HH, bn2_b + l*HH, obuf, 0);

    // ---- combine + FFN ----
    gemm_k<128><<<(NN*256+255)/256, 256, 0, stream>>>(gbuf, obuf, mlp_W1 + l*HH*256, mlp_b1 + l*256, mlph, NN, 256, 1);
    gemm_k<256><<<(NN*HH+255)/256, 256, 0, stream>>>(mlph, nullptr, mlp_W2 + l*256*HH, mlp_b2 + l*HH, mbuf, NN, HH, 0);
    hipMemsetAsync(stats, 0, 256*sizeof(float), stream);
    bn_stats_k<<<64, 256, 0, stream>>>(gbuf, obuf, mbuf, stats);
    bn_apply_k<<<NN*HH/256, 256, 0, stream>>>(gbuf, obuf, mbuf, stats, bn3_g + l*HH, bn3_b + l*HH, h, 1);
  }

  // ---- pool + head MLP ----
  hipMemsetAsync(pooled, 0, (size_t)GG*HH*sizeof(float), stream);
  pool_k<<<NN/2, 256, 0, stream>>>(h, batch, pooled);
  gemm_k<128><<<(GG*HH+255)/256, 256, 0, stream>>>(pooled, nullptr, Wr1, br1, r1, GG, HH, 1);
  gemm_k<128><<<(GG*HH+255)/256, 256, 0, stream>>>(r1, nullptr, Wr2, br2, r2, GG, HH, 1);
  gemm_k<128><<<(GG*10+255)/256, 256, 0, stream>>>(r2, nullptr, Wc, bc, out, GG, 10, 0);
}

// Round 3
// 445.201 us; speedup vs baseline: 3.5741x; 1.6020x over previous
//
#include <hip/hip_runtime.h>
#include <hip/hip_bf16.h>
#include <math.h>

#define NN 4096
#define HH 128
#define EE 65536
#define GG 64
#define KSPLIT 4
#define KLEN (NN / KSPLIT)

typedef unsigned short u16;
typedef unsigned int u32;
typedef __bf16 bf16x8 __attribute__((ext_vector_type(8)));
typedef float f32x4 __attribute__((ext_vector_type(4)));

__device__ inline u16 f2b(float f) {
  u32 u = __float_as_uint(f);
  u += 0x7FFFu + ((u >> 16) & 1u);
  return (u16)(u >> 16);
}
__device__ inline u32 pkbf2(float a, float b) {
  __hip_bfloat162 h = __float22bfloat162_rn(float2{a, b});
  u32 u; __builtin_memcpy(&u, &h, 4); return u;
}

// ---------------- concat+pad prep for input projection ----------------
__global__ __launch_bounds__(256) void xcat_prep_k(
    const float* __restrict__ x, const float* __restrict__ lap,
    const float* __restrict__ rw, float* __restrict__ xcat) {
  int idx = blockIdx.x*256 + threadIdx.x;   // 4096*128
  int n = idx >> 7, c = idx & 127;
  float v = 0.f;
  if (c < 64)      v = x[n*64 + c];
  else if (c < 72) v = lap[n*8 + c - 64];
  else if (c < 88) v = rw[n*16 + c - 72];
  xcat[idx] = v;
}
__global__ __launch_bounds__(256) void wpad_prep_k(
    const float* __restrict__ Wp, float* __restrict__ Wpad) {
  int idx = blockIdx.x*256 + threadIdx.x;   // 128*128
  int r = idx >> 7, c = idx & 127;
  Wpad[idx] = (r < 88) ? Wp[r*HH + c] : 0.f;
}

// ---------------- edge scatter-add: agg[dst] += h[src] ----------------
__global__ __launch_bounds__(256) void edge_agg_k(
    const int* __restrict__ ei, const float* __restrict__ h, float* agg) {
  int e = blockIdx.x*2 + (threadIdx.x >> 7);
  int c = threadIdx.x & 127;
  int s = ei[e], d = ei[EE + e];
  atomicAdd(&agg[d*HH+c], h[s*HH+c]);
}

// ---------------- tiled fp32 GEMM: C = act((A(+A2)) @ B + bias) ----------------
// BM=BN=BK=64, 256 threads (16x16), 4x4 outputs/thread. Nr rows = 4096.
__global__ __launch_bounds__(256) void gemm64_k(
    const float* __restrict__ A, const float* __restrict__ A2,
    const float* __restrict__ B, const float* __restrict__ bias,
    float* __restrict__ C, int K, int M, int act) {
  __shared__ float Ast[64][68];   // [k][n] (transposed)
  __shared__ float Bs[64][68];    // [k][m]
  const int tid = threadIdx.x;
  const int n0 = blockIdx.x * 64, m0 = blockIdx.y * 64;
  const int ty = tid >> 4, tx = tid & 15;
  const int lr = tid >> 4, lc = tid & 15;
  float acc[4][4] = {};

  for (int k0 = 0; k0 < K; k0 += 64) {
    #pragma unroll
    for (int i = 0; i < 4; i++) {
      int r = lr + i*16;
      float4 a4 = *(const float4*)&A[(size_t)(n0 + r)*K + k0 + lc*4];
      if (A2) {
        float4 b4 = *(const float4*)&A2[(size_t)(n0 + r)*K + k0 + lc*4];
        a4.x += b4.x; a4.y += b4.y; a4.z += b4.z; a4.w += b4.w;
      }
      Ast[lc*4+0][r] = a4.x; Ast[lc*4+1][r] = a4.y;
      Ast[lc*4+2][r] = a4.z; Ast[lc*4+3][r] = a4.w;
      *(float4*)&Bs[r][lc*4] = *(const float4*)&B[(size_t)(k0 + r)*M + m0 + lc*4];
    }
    __syncthreads();
    #pragma unroll 4
    for (int k = 0; k < 64; k++) {
      float4 a4 = *(const float4*)&Ast[k][ty*4];
      float4 b4 = *(const float4*)&Bs[k][tx*4];
      acc[0][0] += a4.x*b4.x; acc[0][1] += a4.x*b4.y; acc[0][2] += a4.x*b4.z; acc[0][3] += a4.x*b4.w;
      acc[1][0] += a4.y*b4.x; acc[1][1] += a4.y*b4.y; acc[1][2] += a4.y*b4.z; acc[1][3] += a4.y*b4.w;
      acc[2][0] += a4.z*b4.x; acc[2][1] += a4.z*b4.y; acc[2][2] += a4.z*b4.z; acc[2][3] += a4.z*b4.w;
      acc[3][0] += a4.w*b4.x; acc[3][1] += a4.w*b4.y; acc[3][2] += a4.w*b4.z; acc[3][3] += a4.w*b4.w;
    }
    __syncthreads();
  }
  float b0 = bias[m0+tx*4+0], b1 = bias[m0+tx*4+1];
  float b2 = bias[m0+tx*4+2], b3 = bias[m0+tx*4+3];
  #pragma unroll
  for (int i = 0; i < 4; i++) {
    float4 c4 = make_float4(acc[i][0]+b0, acc[i][1]+b1, acc[i][2]+b2, acc[i][3]+b3);
    if (act) {
      c4.x = fmaxf(c4.x, 0.f); c4.y = fmaxf(c4.y, 0.f);
      c4.z = fmaxf(c4.z, 0.f); c4.w = fmaxf(c4.w, 0.f);
    }
    *(float4*)&C[(size_t)(n0 + ty*4 + i)*M + m0 + tx*4] = c4;
  }
}

// ---------------- qkv GEMM (M=384, K=128) with bf16 q/k/vt epilogue ----------------
__global__ __launch_bounds__(256) void gemm_qkv_k(
    const float* __restrict__ A, const float* __restrict__ B,
    const float* __restrict__ bias, u16* __restrict__ qb,
    u16* __restrict__ kb, u16* __restrict__ vt) {
  __shared__ float Ast[64][68];
  __shared__ float Bs[64][68];
  const int tid = threadIdx.x;
  const int n0 = blockIdx.x * 64, m0 = blockIdx.y * 64;
  const int ty = tid >> 4, tx = tid & 15;
  const int lr = tid >> 4, lc = tid & 15;
  float acc[4][4] = {};

  for (int k0 = 0; k0 < 128; k0 += 64) {
    #pragma unroll
    for (int i = 0; i < 4; i++) {
      int r = lr + i*16;
      float4 a4 = *(const float4*)&A[(size_t)(n0 + r)*128 + k0 + lc*4];
      Ast[lc*4+0][r] = a4.x; Ast[lc*4+1][r] = a4.y;
      Ast[lc*4+2][r] = a4.z; Ast[lc*4+3][r] = a4.w;
      *(float4*)&Bs[r][lc*4] = *(const float4*)&B[(size_t)(k0 + r)*384 + m0 + lc*4];
    }
    __syncthreads();
    #pragma unroll 4
    for (int k = 0; k < 64; k++) {
      float4 a4 = *(const float4*)&Ast[k][ty*4];
      float4 b4 = *(const float4*)&Bs[k][tx*4];
      acc[0][0] += a4.x*b4.x; acc[0][1] += a4.x*b4.y; acc[0][2] += a4.x*b4.z; acc[0][3] += a4.x*b4.w;
      acc[1][0] += a4.y*b4.x; acc[1][1] += a4.y*b4.y; acc[1][2] += a4.y*b4.z; acc[1][3] += a4.y*b4.w;
      acc[2][0] += a4.z*b4.x; acc[2][1] += a4.z*b4.y; acc[2][2] += a4.z*b4.z; acc[2][3] += a4.z*b4.w;
      acc[3][0] += a4.w*b4.x; acc[3][1] += a4.w*b4.y; acc[3][2] += a4.w*b4.z; acc[3][3] += a4.w*b4.w;
    }
    __syncthreads();
  }
  const float QS = 0.17677669529663687f * 1.4426950408889634f;
  float bb[4];
  #pragma unroll
  for (int j = 0; j < 4; j++) bb[j] = bias[m0 + tx*4 + j];
  int c0 = m0 + tx*4;
  if (c0 < 128) {           // Q: scaled
    int head = c0 >> 5, d = c0 & 31;
    #pragma unroll
    for (int i = 0; i < 4; i++) {
      int n = n0 + ty*4 + i;
      ushort4 s;
      s.x = f2b((acc[i][0]+bb[0])*QS); s.y = f2b((acc[i][1]+bb[1])*QS);
      s.z = f2b((acc[i][2]+bb[2])*QS); s.w = f2b((acc[i][3]+bb[3])*QS);
      *(ushort4*)&qb[((size_t)head*NN + n)*32 + d] = s;
    }
  } else if (c0 < 256) {    // K
    int cc = c0 - 128;
    int head = cc >> 5, d = cc & 31;
    #pragma unroll
    for (int i = 0; i < 4; i++) {
      int n = n0 + ty*4 + i;
      ushort4 s;
      s.x = f2b(acc[i][0]+bb[0]); s.y = f2b(acc[i][1]+bb[1]);
      s.z = f2b(acc[i][2]+bb[2]); s.w = f2b(acc[i][3]+bb[3]);
      *(ushort4*)&kb[((size_t)head*NN + n)*32 + d] = s;
    }
  } else {                  // V transposed: vt[c][n]
    int cc = c0 - 256;
    #pragma unroll
    for (int j = 0; j < 4; j++) {
      ushort4 s;
      s.x = f2b(acc[0][j]+bb[j]); s.y = f2b(acc[1][j]+bb[j]);
      s.z = f2b(acc[2][j]+bb[j]); s.w = f2b(acc[3][j]+bb[j]);
      *(ushort4*)&vt[(size_t)(cc + j)*NN + n0 + ty*4] = s;
    }
  }
}

// ---------------- small naive GEMM for the 64-row head ----------------
template <int K>
__global__ __launch_bounds__(256) void gemm_k(
    const float* __restrict__ A, const float* __restrict__ B,
    const float* __restrict__ bias, float* __restrict__ C,
    int Nr, int M, int act) {
  int idx = blockIdx.x*256 + threadIdx.x;
  if (idx >= Nr*M) return;
  int n = idx / M, mm = idx - n*M;
  float acc = bias[mm];
  #pragma unroll 8
  for (int k = 0; k < K; k++) acc += A[n*K+k] * B[k*M+mm];
  C[idx] = act ? fmaxf(acc, 0.f) : acc;
}

// ---------------- BN: per-channel sum / sumsq over (x1+x2+x3) ----------------
__global__ __launch_bounds__(256) void bn_stats_k(
    const float* __restrict__ x1, const float* __restrict__ x2,
    const float* __restrict__ x3, float* stats) {
  __shared__ float ss[256], sq[256];
  int c = threadIdx.x & 127, half = threadIdx.x >> 7;
  float s = 0.f, q = 0.f;
  int base = blockIdx.x * 64;
  for (int n = base + half; n < base + 64; n += 2) {
    float v = x1[n*HH+c];
    if (x2) v += x2[n*HH+c];
    if (x3) v += x3[n*HH+c];
    s += v; q += v*v;
  }
  ss[threadIdx.x] = s; sq[threadIdx.x] = q;
  __syncthreads();
  if (threadIdx.x < 128) {
    atomicAdd(&stats[c],       ss[threadIdx.x] + ss[threadIdx.x+128]);
    atomicAdd(&stats[128+c],   sq[threadIdx.x] + sq[threadIdx.x+128]);
  }
}

__global__ __launch_bounds__(256) void bn_apply_k(
    const float* __restrict__ x1, const float* __restrict__ x2,
    const float* __restrict__ x3, const float* __restrict__ stats,
    const float* __restrict__ gamma, const float* __restrict__ beta,
    float* __restrict__ y, int act) {
  int idx = blockIdx.x*256 + threadIdx.x;
  int c = idx & 127;
  float mean = stats[c] * (1.f/NN);
  float var  = stats[128+c] * (1.f/NN) - mean*mean;
  float rs = rsqrtf(var + 1e-5f);
  float v = x1[idx];
  if (x2) v += x2[idx];
  if (x3) v += x3[idx];
  float r = (v - mean) * rs * gamma[c] + beta[c];
  y[idx] = act ? fmaxf(r, 0.f) : r;
}

// ---------------- MFMA flash attention ----------------
// grid (KSPLIT, NN/64, 4 heads), block 256 (4 waves, 16 queries each).
__global__ __launch_bounds__(256) void mfma_attn_k(
    const u16* __restrict__ qb, const u16* __restrict__ kb,
    const u16* __restrict__ vt, float* __restrict__ opart,
    float* __restrict__ mlpart) {
  __shared__ __align__(16) u16 pbuf[4][1024];  // [w][16 rows][64 cols], XOR-swizzled
  __shared__ float corrbuf[4][16];

  const int w = threadIdx.x >> 6, lane = threadIdx.x & 63;
  const int g = lane >> 4, li = lane & 15;
  const int head = blockIdx.z;
  const int q0 = blockIdx.y * 64 + w * 16;
  const int j0 = blockIdx.x * KLEN;

  const bf16x8 qf = *reinterpret_cast<const bf16x8*>(
      qb + ((size_t)(head*NN) + q0 + li)*32 + g*8);

  f32x4 oacc0 = {0.f,0.f,0.f,0.f}, oacc1 = {0.f,0.f,0.f,0.f};
  const f32x4 zz = {0.f,0.f,0.f,0.f};
  float m = -1e30f, lsum = 0.f;
  char* pb = (char*)&pbuf[w][0];
  const int swz = (li & 7) << 4;

  for (int jt = j0; jt < j0 + KLEN; jt += 64) {
    f32x4 st[4];
    #pragma unroll
    for (int t = 0; t < 4; t++) {
      bf16x8 kf = *reinterpret_cast<const bf16x8*>(
          kb + ((size_t)(head*NN) + jt + t*16 + li)*32 + g*8);
      st[t] = __builtin_amdgcn_mfma_f32_16x16x32_bf16(kf, qf, zz, 0, 0, 0);
    }
    float tm = st[0][0];
    #pragma unroll
    for (int t = 0; t < 4; t++)
      #pragma unroll
      for (int r = 0; r < 4; r++) tm = fmaxf(tm, st[t][r]);
    tm = fmaxf(tm, __shfl_xor(tm, 16));
    tm = fmaxf(tm, __shfl_xor(tm, 32));
    float mnew = fmaxf(m, tm);
    float corr = exp2f(m - mnew);
    m = mnew;
    lsum *= corr;
    #pragma unroll
    for (int t = 0; t < 4; t++) {
      float p0 = exp2f(st[t][0] - m), p1 = exp2f(st[t][1] - m);
      float p2 = exp2f(st[t][2] - m), p3 = exp2f(st[t][3] - m);
      lsum += p0 + p1 + p2 + p3;
      uint2 wv;
      wv.x = pkbf2(p0, p1);
      wv.y = pkbf2(p2, p3);
      *reinterpret_cast<uint2*>(pb + ((li*128 + t*32 + g*8) ^ swz)) = wv;
    }
    if (lane < 16) corrbuf[w][lane] = corr;
    f32x4 cv = *reinterpret_cast<f32x4*>(&corrbuf[w][g*4]);
    #pragma unroll
    for (int r = 0; r < 4; r++) { oacc0[r] *= cv[r]; oacc1[r] *= cv[r]; }
    #pragma unroll
    for (int c = 0; c < 2; c++) {
      bf16x8 pa = *reinterpret_cast<const bf16x8*>(pb + ((li*128 + c*64 + g*16) ^ swz));
      const u16* vrow = vt + ((size_t)(head*32 + li))*NN + jt + c*32 + g*8;
      bf16x8 vb0 = *reinterpret_cast<const bf16x8*>(vrow);
      bf16x8 vb1 = *reinterpret_cast<const bf16x8*>(vrow + (size_t)16*NN);
      oacc0 = __builtin_amdgcn_mfma_f32_16x16x32_bf16(pa, vb0, oacc0, 0, 0, 0);
      oacc1 = __builtin_amdgcn_mfma_f32_16x16x32_bf16(pa, vb1, oacc1, 0, 0, 0);
    }
  }
  lsum += __shfl_xor(lsum, 16);
  lsum += __shfl_xor(lsum, 32);

  size_t b = (size_t)(blockIdx.x*4 + head)*NN + q0;
  #pragma unroll
  for (int r = 0; r < 4; r++) {
    size_t ob = (b + 4*g + r)*32;
    opart[ob + li]      = oacc0[r];
    opart[ob + 16 + li] = oacc1[r];
  }
  if (lane < 16) {
    size_t bb = (b + lane)*2;
    mlpart[bb]   = m;
    mlpart[bb+1] = lsum;
  }
}

// combine KSPLIT partials -> attno[n, head*32+d]  (log2 domain)
__global__ __launch_bounds__(256) void attn_merge_k(
    const float* __restrict__ opart, const float* __restrict__ mlpart,
    float* __restrict__ attno) {
  int idx = blockIdx.x*256 + threadIdx.x;   // 4*NN*32
  int d = idx & 31;
  int n = (idx >> 5) & (NN-1);
  int head = idx >> 17;
  float M = -1e30f;
  #pragma unroll
  for (int s = 0; s < KSPLIT; s++)
    M = fmaxf(M, mlpart[((size_t)(s*4+head)*NN + n)*2]);
  float L = 0.f, O = 0.f;
  #pragma unroll
  for (int s = 0; s < KSPLIT; s++) {
    size_t b = (size_t)(s*4+head)*NN + n;
    float wgt = exp2f(mlpart[b*2] - M);
    L += mlpart[b*2+1] * wgt;
    O += opart[b*32 + d] * wgt;
  }
  attno[n*HH + head*32 + d] = O / L;
}

// ---------------- global add pool ----------------
__global__ __launch_bounds__(256) void pool_k(
    const float* __restrict__ h, const int* __restrict__ batch, float* pooled) {
  int n = blockIdx.x*2 + (threadIdx.x >> 7);
  int c = threadIdx.x & 127;
  atomicAdd(&pooled[batch[n]*HH+c], h[n*HH+c]);
}

extern "C" void kernel_launch(void* const* d_in, const int* in_sizes, int n_in,
                              void* d_out, int out_size, void* d_ws, size_t ws_size,
                              hipStream_t stream) {
  const float* x      = (const float*)d_in[0];
  const float* lap    = (const float*)d_in[1];
  const float* rw     = (const float*)d_in[2];
  const int*   ei     = (const int*)d_in[3];
  const int*   batch  = (const int*)d_in[4];
  const float* Wp     = (const float*)d_in[5];
  const float* bp     = (const float*)d_in[6];
  const float* gin_W1 = (const float*)d_in[7];
  const float* gin_b1 = (const float*)d_in[8];
  const float* gin_W2 = (const float*)d_in[9];
  const float* gin_b2 = (const float*)d_in[10];
  const float* bn1_g  = (const float*)d_in[11];
  const float* bn1_b  = (const float*)d_in[12];
  const float* bn2_g  = (const float*)d_in[13];
  const float* bn2_b  = (const float*)d_in[14];
  const float* bn3_g  = (const float*)d_in[15];
  const float* bn3_b  = (const float*)d_in[16];
  const float* ain_w  = (const float*)d_in[17];
  const float* ain_b  = (const float*)d_in[18];
  const float* aout_w = (const float*)d_in[19];
  const float* aout_b = (const float*)d_in[20];
  const float* mlp_W1 = (const float*)d_in[21];
  const float* mlp_b1 = (const float*)d_in[22];
  const float* mlp_W2 = (const float*)d_in[23];
  const float* mlp_b2 = (const float*)d_in[24];
  const float* Wr1    = (const float*)d_in[25];
  const float* br1    = (const float*)d_in[26];
  const float* Wr2    = (const float*)d_in[27];
  const float* br2    = (const float*)d_in[28];
  const float* Wc     = (const float*)d_in[29];
  const float* bc     = (const float*)d_in[30];
  float* out = (float*)d_out;

  float* w = (float*)d_ws;
  float* h      = w + 0;          // 524288
  float* agg    = w + 524288;     // 524288
  float* gtmp   = w + 1048576;    // 524288
  float* gbuf   = w + 1572864;    // 524288
  float* attno  = w + 2097152;    // 524288
  float* obuf   = w + 2621440;    // 524288
  float* mlph   = w + 3145728;    // 1048576
  float* mbuf   = w + 4194304;    // 524288
  float* opart  = w + 4718592;    // 2097152
  float* mlpart = w + 6815744;    // 131072
  float* stats  = w + 6946816;    // 256
  float* pooled = w + 6947072;    // 8192
  float* r1     = w + 6955264;    // 8192
  float* r2     = w + 6963456;    // 8192
  float* xcat   = w + 6971648;    // 524288
  float* wppad  = w + 7495936;    // 16384
  u16*   qb     = (u16*)(w + 7512320);  // 524288 u16
  u16*   kb     = (u16*)(w + 7774464);
  u16*   vt     = (u16*)(w + 8036608);

  xcat_prep_k<<<NN*HH/256, 256, 0, stream>>>(x, lap, rw, xcat);
  wpad_prep_k<<<HH*HH/256, 256, 0, stream>>>(Wp, wppad);
  gemm64_k<<<dim3(64, 2), 256, 0, stream>>>(xcat, nullptr, wppad, bp, h, 128, 128, 0);

  for (int l = 0; l < 2; l++) {
    // ---- GIN branch ----
    hipMemsetAsync(agg, 0, (size_t)NN*HH*sizeof(float), stream);
    edge_agg_k<<<EE/2, 256, 0, stream>>>(ei, h, agg);
    gemm64_k<<<dim3(64, 2), 256, 0, stream>>>(h, agg, gin_W1 + l*HH*HH, gin_b1 + l*HH, gtmp, 128, 128, 1);
    gemm64_k<<<dim3(64, 2), 256, 0, stream>>>(gtmp, nullptr, gin_W2 + l*HH*HH, gin_b2 + l*HH, mbuf, 128, 128, 0);
    hipMemsetAsync(stats, 0, 256*sizeof(float), stream);
    bn_stats_k<<<64, 256, 0, stream>>>(mbuf, h, nullptr, stats);
    bn_apply_k<<<NN*HH/256, 256, 0, stream>>>(mbuf, h, nullptr, stats, bn1_g + l*HH, bn1_b + l*HH, gbuf, 0);

    // ---- attention branch ----
    gemm_qkv_k<<<dim3(64, 6), 256, 0, stream>>>(h, ain_w + l*HH*384, ain_b + l*384, qb, kb, vt);
    dim3 fgrid(KSPLIT, NN/64, 4);
    mfma_attn_k<<<fgrid, 256, 0, stream>>>(qb, kb, vt, opart, mlpart);
    attn_merge_k<<<(4*NN*32)/256, 256, 0, stream>>>(opart, mlpart, attno);
    gemm64_k<<<dim3(64, 2), 256, 0, stream>>>(attno, nullptr, aout_w + l*HH*HH, aout_b + l*HH, gtmp, 128, 128, 0);
    hipMemsetAsync(stats, 0, 256*sizeof(float), stream);
    bn_stats_k<<<64, 256, 0, stream>>>(gtmp, h, nullptr, stats);
    bn_apply_k<<<NN*HH/256, 256, 0, stream>>>(gtmp, h, nullptr, stats, bn2_g + l*HH, bn2_b + l*HH, obuf, 0);

    // ---- combine + FFN ----
    gemm64_k<<<dim3(64, 4), 256, 0, stream>>>(gbuf, obuf, mlp_W1 + l*HH*256, mlp_b1 + l*256, mlph, 128, 256, 1);
    gemm64_k<<<dim3(64, 2), 256, 0, stream>>>(mlph, nullptr, mlp_W2 + l*256*HH, mlp_b2 + l*HH, mbuf, 256, 128, 0);
    hipMemsetAsync(stats, 0, 256*sizeof(float), stream);
    bn_stats_k<<<64, 256, 0, stream>>>(gbuf, obuf, mbuf, stats);
    bn_apply_k<<<NN*HH/256, 256, 0, stream>>>(gbuf, obuf, mbuf, stats, bn3_g + l*HH, bn3_b + l*HH, h, 1);
  }

  // ---- pool + head MLP ----
  hipMemsetAsync(pooled, 0, (size_t)GG*HH*sizeof(float), stream);
  pool_k<<<NN/2, 256, 0, stream>>>(h, batch, pooled);
  gemm_k<128><<<(GG*HH+255)/256, 256, 0, stream>>>(pooled, Wr1, br1, r1, GG, HH, 1);
  gemm_k<128><<<(GG*HH+255)/256, 256, 0, stream>>>(r1, Wr2, br2, r2, GG, HH, 1);
  gemm_k<128><<<(GG*10+255)/256, 256, 0, stream>>>(r2, Wc, bc, out, GG, 10, 0);
}

// Round 4
// 380.006 us; speedup vs baseline: 4.1873x; 1.1716x over previous
//
#include <hip/hip_runtime.h>
#include <hip/hip_bf16.h>
#include <math.h>

#define NN 4096
#define HH 128
#define EE 65536
#define GG 64
#define KSPLIT 8
#define KLEN (NN / KSPLIT)

typedef unsigned short u16;
typedef unsigned int u32;
typedef __bf16 bf16x8 __attribute__((ext_vector_type(8)));
typedef float f32x4 __attribute__((ext_vector_type(4)));

__device__ inline u16 f2b(float f) {
  u32 u = __float_as_uint(f);
  u += 0x7FFFu + ((u >> 16) & 1u);
  return (u16)(u >> 16);
}
__device__ inline u32 pkbf2(float a, float b) {
  __hip_bfloat162 h = __float22bfloat162_rn(float2{a, b});
  u32 u; __builtin_memcpy(&u, &h, 4); return u;
}

// ---------------- concat+pad prep for input projection ----------------
__global__ __launch_bounds__(256) void xcat_prep_k(
    const float* __restrict__ x, const float* __restrict__ lap,
    const float* __restrict__ rw, float* __restrict__ xcat) {
  int idx = blockIdx.x*256 + threadIdx.x;   // 4096*128
  int n = idx >> 7, c = idx & 127;
  float v = 0.f;
  if (c < 64)      v = x[n*64 + c];
  else if (c < 72) v = lap[n*8 + c - 64];
  else if (c < 88) v = rw[n*16 + c - 72];
  xcat[idx] = v;
}
__global__ __launch_bounds__(256) void wpad_prep_k(
    const float* __restrict__ Wp, float* __restrict__ Wpad) {
  int idx = blockIdx.x*256 + threadIdx.x;   // 128*128
  int r = idx >> 7, c = idx & 127;
  Wpad[idx] = (r < 88) ? Wp[r*HH + c] : 0.f;
}

// ---------------- edge scatter-add: agg[dst] += h[src] ----------------
__global__ __launch_bounds__(256) void edge_agg_k(
    const int* __restrict__ ei, const float* __restrict__ h, float* agg) {
  int e = blockIdx.x*2 + (threadIdx.x >> 7);
  int c = threadIdx.x & 127;
  int s = ei[e], d = ei[EE + e];
  atomicAdd(&agg[d*HH+c], h[s*HH+c]);
}

// ---------------- tiled fp32 GEMM: C = act((A(+A2)) @ B + bias) ----------------
__global__ __launch_bounds__(256) void gemm64_k(
    const float* __restrict__ A, const float* __restrict__ A2,
    const float* __restrict__ B, const float* __restrict__ bias,
    float* __restrict__ C, int K, int M, int act) {
  __shared__ float Ast[64][68];
  __shared__ float Bs[64][68];
  const int tid = threadIdx.x;
  const int n0 = blockIdx.x * 64, m0 = blockIdx.y * 64;
  const int ty = tid >> 4, tx = tid & 15;
  const int lr = tid >> 4, lc = tid & 15;
  float acc[4][4] = {};

  for (int k0 = 0; k0 < K; k0 += 64) {
    #pragma unroll
    for (int i = 0; i < 4; i++) {
      int r = lr + i*16;
      float4 a4 = *(const float4*)&A[(size_t)(n0 + r)*K + k0 + lc*4];
      if (A2) {
        float4 b4 = *(const float4*)&A2[(size_t)(n0 + r)*K + k0 + lc*4];
        a4.x += b4.x; a4.y += b4.y; a4.z += b4.z; a4.w += b4.w;
      }
      Ast[lc*4+0][r] = a4.x; Ast[lc*4+1][r] = a4.y;
      Ast[lc*4+2][r] = a4.z; Ast[lc*4+3][r] = a4.w;
      *(float4*)&Bs[r][lc*4] = *(const float4*)&B[(size_t)(k0 + r)*M + m0 + lc*4];
    }
    __syncthreads();
    #pragma unroll 4
    for (int k = 0; k < 64; k++) {
      float4 a4 = *(const float4*)&Ast[k][ty*4];
      float4 b4 = *(const float4*)&Bs[k][tx*4];
      acc[0][0] += a4.x*b4.x; acc[0][1] += a4.x*b4.y; acc[0][2] += a4.x*b4.z; acc[0][3] += a4.x*b4.w;
      acc[1][0] += a4.y*b4.x; acc[1][1] += a4.y*b4.y; acc[1][2] += a4.y*b4.z; acc[1][3] += a4.y*b4.w;
      acc[2][0] += a4.z*b4.x; acc[2][1] += a4.z*b4.y; acc[2][2] += a4.z*b4.z; acc[2][3] += a4.z*b4.w;
      acc[3][0] += a4.w*b4.x; acc[3][1] += a4.w*b4.y; acc[3][2] += a4.w*b4.z; acc[3][3] += a4.w*b4.w;
    }
    __syncthreads();
  }
  float b0 = bias[m0+tx*4+0], b1 = bias[m0+tx*4+1];
  float b2 = bias[m0+tx*4+2], b3 = bias[m0+tx*4+3];
  #pragma unroll
  for (int i = 0; i < 4; i++) {
    float4 c4 = make_float4(acc[i][0]+b0, acc[i][1]+b1, acc[i][2]+b2, acc[i][3]+b3);
    if (act) {
      c4.x = fmaxf(c4.x, 0.f); c4.y = fmaxf(c4.y, 0.f);
      c4.z = fmaxf(c4.z, 0.f); c4.w = fmaxf(c4.w, 0.f);
    }
    *(float4*)&C[(size_t)(n0 + ty*4 + i)*M + m0 + tx*4] = c4;
  }
}

// ---- GEMM + residual + per-channel stats (sum, sumsq) epilogue (K=128,M=128)
__global__ __launch_bounds__(256) void gemm64_resstat_k(
    const float* __restrict__ A, const float* __restrict__ B,
    const float* __restrict__ bias, const float* __restrict__ res,
    float* __restrict__ C, float* __restrict__ stats) {
  __shared__ float Ast[64][68];
  __shared__ float Bs[64][68];
  const int tid = threadIdx.x;
  const int n0 = blockIdx.x * 64, m0 = blockIdx.y * 64;
  const int ty = tid >> 4, tx = tid & 15;
  const int lr = tid >> 4, lc = tid & 15;
  float acc[4][4] = {};

  for (int k0 = 0; k0 < 128; k0 += 64) {
    #pragma unroll
    for (int i = 0; i < 4; i++) {
      int r = lr + i*16;
      float4 a4 = *(const float4*)&A[(size_t)(n0 + r)*128 + k0 + lc*4];
      Ast[lc*4+0][r] = a4.x; Ast[lc*4+1][r] = a4.y;
      Ast[lc*4+2][r] = a4.z; Ast[lc*4+3][r] = a4.w;
      *(float4*)&Bs[r][lc*4] = *(const float4*)&B[(size_t)(k0 + r)*128 + m0 + lc*4];
    }
    __syncthreads();
    #pragma unroll 4
    for (int k = 0; k < 64; k++) {
      float4 a4 = *(const float4*)&Ast[k][ty*4];
      float4 b4 = *(const float4*)&Bs[k][tx*4];
      acc[0][0] += a4.x*b4.x; acc[0][1] += a4.x*b4.y; acc[0][2] += a4.x*b4.z; acc[0][3] += a4.x*b4.w;
      acc[1][0] += a4.y*b4.x; acc[1][1] += a4.y*b4.y; acc[1][2] += a4.y*b4.z; acc[1][3] += a4.y*b4.w;
      acc[2][0] += a4.z*b4.x; acc[2][1] += a4.z*b4.y; acc[2][2] += a4.z*b4.z; acc[2][3] += a4.z*b4.w;
      acc[3][0] += a4.w*b4.x; acc[3][1] += a4.w*b4.y; acc[3][2] += a4.w*b4.z; acc[3][3] += a4.w*b4.w;
    }
    __syncthreads();
  }
  float4 bb = *(const float4*)&bias[m0 + tx*4];
  float4 csum = {0,0,0,0}, csq = {0,0,0,0};
  #pragma unroll
  for (int i = 0; i < 4; i++) {
    int row = n0 + ty*4 + i;
    float4 r4 = *(const float4*)&res[(size_t)row*128 + m0 + tx*4];
    float4 v = make_float4(acc[i][0]+bb.x+r4.x, acc[i][1]+bb.y+r4.y,
                           acc[i][2]+bb.z+r4.z, acc[i][3]+bb.w+r4.w);
    *(float4*)&C[(size_t)row*128 + m0 + tx*4] = v;
    csum.x += v.x; csum.y += v.y; csum.z += v.z; csum.w += v.w;
    csq.x += v.x*v.x; csq.y += v.y*v.y; csq.z += v.z*v.z; csq.w += v.w*v.w;
  }
  float4* red = (float4*)&Ast[0][0];
  red[ty*16 + tx] = csum;
  red[256 + ty*16 + tx] = csq;
  __syncthreads();
  if (tid < 16) {
    float4 s = {0,0,0,0}, q = {0,0,0,0};
    #pragma unroll
    for (int t = 0; t < 16; t++) {
      float4 a = red[t*16 + tid], b = red[256 + t*16 + tid];
      s.x+=a.x; s.y+=a.y; s.z+=a.z; s.w+=a.w;
      q.x+=b.x; q.y+=b.y; q.z+=b.z; q.w+=b.w;
    }
    int c = m0 + tid*4;
    atomicAdd(&stats[c+0], s.x); atomicAdd(&stats[c+1], s.y);
    atomicAdd(&stats[c+2], s.z); atomicAdd(&stats[c+3], s.w);
    atomicAdd(&stats[128+c+0], q.x); atomicAdd(&stats[128+c+1], q.y);
    atomicAdd(&stats[128+c+2], q.z); atomicAdd(&stats[128+c+3], q.w);
  }
}

// ---- FFN1: mlph = relu( (BN1(pre1)+BN2(pre2)) @ B + bias ), K=128, M=256
__global__ __launch_bounds__(256) void gemm64_aff_k(
    const float* __restrict__ pre1, const float* __restrict__ pre2,
    const float* __restrict__ aff, const float* __restrict__ B,
    const float* __restrict__ bias, float* __restrict__ C) {
  __shared__ float Ast[64][68];
  __shared__ float Bs[64][68];
  const int tid = threadIdx.x;
  const int n0 = blockIdx.x * 64, m0 = blockIdx.y * 64;
  const int ty = tid >> 4, tx = tid & 15;
  const int lr = tid >> 4, lc = tid & 15;
  float acc[4][4] = {};

  for (int k0 = 0; k0 < 128; k0 += 64) {
    float4 s1 = *(const float4*)&aff[k0 + lc*4];
    float4 t1 = *(const float4*)&aff[128 + k0 + lc*4];
    float4 s2 = *(const float4*)&aff[256 + k0 + lc*4];
    float4 t2 = *(const float4*)&aff[384 + k0 + lc*4];
    #pragma unroll
    for (int i = 0; i < 4; i++) {
      int r = lr + i*16;
      float4 p1 = *(const float4*)&pre1[(size_t)(n0 + r)*128 + k0 + lc*4];
      float4 p2 = *(const float4*)&pre2[(size_t)(n0 + r)*128 + k0 + lc*4];
      Ast[lc*4+0][r] = p1.x*s1.x + t1.x + p2.x*s2.x + t2.x;
      Ast[lc*4+1][r] = p1.y*s1.y + t1.y + p2.y*s2.y + t2.y;
      Ast[lc*4+2][r] = p1.z*s1.z + t1.z + p2.z*s2.z + t2.z;
      Ast[lc*4+3][r] = p1.w*s1.w + t1.w + p2.w*s2.w + t2.w;
      *(float4*)&Bs[r][lc*4] = *(const float4*)&B[(size_t)(k0 + r)*256 + m0 + lc*4];
    }
    __syncthreads();
    #pragma unroll 4
    for (int k = 0; k < 64; k++) {
      float4 a4 = *(const float4*)&Ast[k][ty*4];
      float4 b4 = *(const float4*)&Bs[k][tx*4];
      acc[0][0] += a4.x*b4.x; acc[0][1] += a4.x*b4.y; acc[0][2] += a4.x*b4.z; acc[0][3] += a4.x*b4.w;
      acc[1][0] += a4.y*b4.x; acc[1][1] += a4.y*b4.y; acc[1][2] += a4.y*b4.z; acc[1][3] += a4.y*b4.w;
      acc[2][0] += a4.z*b4.x; acc[2][1] += a4.z*b4.y; acc[2][2] += a4.z*b4.z; acc[2][3] += a4.z*b4.w;
      acc[3][0] += a4.w*b4.x; acc[3][1] += a4.w*b4.y; acc[3][2] += a4.w*b4.z; acc[3][3] += a4.w*b4.w;
    }
    __syncthreads();
  }
  float4 bb = *(const float4*)&bias[m0 + tx*4];
  #pragma unroll
  for (int i = 0; i < 4; i++) {
    float4 c4 = make_float4(fmaxf(acc[i][0]+bb.x, 0.f), fmaxf(acc[i][1]+bb.y, 0.f),
                            fmaxf(acc[i][2]+bb.z, 0.f), fmaxf(acc[i][3]+bb.w, 0.f));
    *(float4*)&C[(size_t)(n0 + ty*4 + i)*256 + m0 + tx*4] = c4;
  }
}

// ---- FFN2: out3 = mlph@B + bias + BN1(pre1)+BN2(pre2), stats3. K=256, M=128
__global__ __launch_bounds__(256) void gemm64_s3_k(
    const float* __restrict__ A, const float* __restrict__ B,
    const float* __restrict__ bias, const float* __restrict__ pre1,
    const float* __restrict__ pre2, const float* __restrict__ aff,
    float* __restrict__ out3, float* __restrict__ stats) {
  __shared__ float Ast[64][68];
  __shared__ float Bs[64][68];
  const int tid = threadIdx.x;
  const int n0 = blockIdx.x * 64, m0 = blockIdx.y * 64;
  const int ty = tid >> 4, tx = tid & 15;
  const int lr = tid >> 4, lc = tid & 15;
  float acc[4][4] = {};

  for (int k0 = 0; k0 < 256; k0 += 64) {
    #pragma unroll
    for (int i = 0; i < 4; i++) {
      int r = lr + i*16;
      float4 a4 = *(const float4*)&A[(size_t)(n0 + r)*256 + k0 + lc*4];
      Ast[lc*4+0][r] = a4.x; Ast[lc*4+1][r] = a4.y;
      Ast[lc*4+2][r] = a4.z; Ast[lc*4+3][r] = a4.w;
      *(float4*)&Bs[r][lc*4] = *(const float4*)&B[(size_t)(k0 + r)*128 + m0 + lc*4];
    }
    __syncthreads();
    #pragma unroll 4
    for (int k = 0; k < 64; k++) {
      float4 a4 = *(const float4*)&Ast[k][ty*4];
      float4 b4 = *(const float4*)&Bs[k][tx*4];
      acc[0][0] += a4.x*b4.x; acc[0][1] += a4.x*b4.y; acc[0][2] += a4.x*b4.z; acc[0][3] += a4.x*b4.w;
      acc[1][0] += a4.y*b4.x; acc[1][1] += a4.y*b4.y; acc[1][2] += a4.y*b4.z; acc[1][3] += a4.y*b4.w;
      acc[2][0] += a4.z*b4.x; acc[2][1] += a4.z*b4.y; acc[2][2] += a4.z*b4.z; acc[2][3] += a4.z*b4.w;
      acc[3][0] += a4.w*b4.x; acc[3][1] += a4.w*b4.y; acc[3][2] += a4.w*b4.z; acc[3][3] += a4.w*b4.w;
    }
    __syncthreads();
  }
  float4 bb = *(const float4*)&bias[m0 + tx*4];
  float4 s1 = *(const float4*)&aff[m0 + tx*4];
  float4 t1 = *(const float4*)&aff[128 + m0 + tx*4];
  float4 s2 = *(const float4*)&aff[256 + m0 + tx*4];
  float4 t2 = *(const float4*)&aff[384 + m0 + tx*4];
  float4 csum = {0,0,0,0}, csq = {0,0,0,0};
  #pragma unroll
  for (int i = 0; i < 4; i++) {
    int row = n0 + ty*4 + i;
    float4 p1 = *(const float4*)&pre1[(size_t)row*128 + m0 + tx*4];
    float4 p2 = *(const float4*)&pre2[(size_t)row*128 + m0 + tx*4];
    float4 v;
    v.x = acc[i][0]+bb.x + p1.x*s1.x+t1.x + p2.x*s2.x+t2.x;
    v.y = acc[i][1]+bb.y + p1.y*s1.y+t1.y + p2.y*s2.y+t2.y;
    v.z = acc[i][2]+bb.z + p1.z*s1.z+t1.z + p2.z*s2.z+t2.z;
    v.w = acc[i][3]+bb.w + p1.w*s1.w+t1.w + p2.w*s2.w+t2.w;
    *(float4*)&out3[(size_t)row*128 + m0 + tx*4] = v;
    csum.x += v.x; csum.y += v.y; csum.z += v.z; csum.w += v.w;
    csq.x += v.x*v.x; csq.y += v.y*v.y; csq.z += v.z*v.z; csq.w += v.w*v.w;
  }
  float4* red = (float4*)&Ast[0][0];
  red[ty*16 + tx] = csum;
  red[256 + ty*16 + tx] = csq;
  __syncthreads();
  if (tid < 16) {
    float4 s = {0,0,0,0}, q = {0,0,0,0};
    #pragma unroll
    for (int t = 0; t < 16; t++) {
      float4 a = red[t*16 + tid], b = red[256 + t*16 + tid];
      s.x+=a.x; s.y+=a.y; s.z+=a.z; s.w+=a.w;
      q.x+=b.x; q.y+=b.y; q.z+=b.z; q.w+=b.w;
    }
    int c = m0 + tid*4;
    atomicAdd(&stats[c+0], s.x); atomicAdd(&stats[c+1], s.y);
    atomicAdd(&stats[c+2], s.z); atomicAdd(&stats[c+3], s.w);
    atomicAdd(&stats[128+c+0], q.x); atomicAdd(&stats[128+c+1], q.y);
    atomicAdd(&stats[128+c+2], q.z); atomicAdd(&stats[128+c+3], q.w);
  }
}

// ---- affine params from stats: s = rsqrt(var+eps)*gamma, t = beta - mean*s
__global__ __launch_bounds__(256) void prep_aff_k(
    const float* __restrict__ stats1, const float* __restrict__ stats2,
    const float* __restrict__ g1, const float* __restrict__ b1,
    const float* __restrict__ g2, const float* __restrict__ b2,
    float* __restrict__ aff) {
  int c = threadIdx.x;            // 0..255
  int cc = c & 127;
  const float* st = (c < 128) ? stats1 : stats2;
  const float* gg = (c < 128) ? g1 : g2;
  const float* bb = (c < 128) ? b1 : b2;
  float mean = st[cc] * (1.f/NN);
  float var  = st[128+cc] * (1.f/NN) - mean*mean;
  float s = rsqrtf(var + 1e-5f) * gg[cc];
  int base = (c < 128) ? 0 : 256;
  aff[base + cc]       = s;
  aff[base + 128 + cc] = bb[cc] - mean*s;
}

// ---- BN3 apply (+relu) -> h; optionally pool instead of writing h
__global__ __launch_bounds__(256) void bn3_k(
    const float* __restrict__ out3, const float* __restrict__ stats,
    const float* __restrict__ gamma, const float* __restrict__ beta,
    float* __restrict__ h, const int* __restrict__ batch,
    float* __restrict__ pooled, int dopool) {
  int idx = blockIdx.x*256 + threadIdx.x;
  int c = idx & 127;
  float mean = stats[c] * (1.f/NN);
  float var  = stats[128+c] * (1.f/NN) - mean*mean;
  float rs = rsqrtf(var + 1e-5f);
  float r = fmaxf((out3[idx] - mean) * rs * gamma[c] + beta[c], 0.f);
  if (dopool) atomicAdd(&pooled[batch[idx >> 7]*HH + c], r);
  else        h[idx] = r;
}

// ---------------- qkv GEMM (M=384, K=128) with bf16 q/k/vt epilogue ----------------
__global__ __launch_bounds__(256) void gemm_qkv_k(
    const float* __restrict__ A, const float* __restrict__ B,
    const float* __restrict__ bias, u16* __restrict__ qb,
    u16* __restrict__ kb, u16* __restrict__ vt) {
  __shared__ float Ast[64][68];
  __shared__ float Bs[64][68];
  const int tid = threadIdx.x;
  const int n0 = blockIdx.x * 64, m0 = blockIdx.y * 64;
  const int ty = tid >> 4, tx = tid & 15;
  const int lr = tid >> 4, lc = tid & 15;
  float acc[4][4] = {};

  for (int k0 = 0; k0 < 128; k0 += 64) {
    #pragma unroll
    for (int i = 0; i < 4; i++) {
      int r = lr + i*16;
      float4 a4 = *(const float4*)&A[(size_t)(n0 + r)*128 + k0 + lc*4];
      Ast[lc*4+0][r] = a4.x; Ast[lc*4+1][r] = a4.y;
      Ast[lc*4+2][r] = a4.z; Ast[lc*4+3][r] = a4.w;
      *(float4*)&Bs[r][lc*4] = *(const float4*)&B[(size_t)(k0 + r)*384 + m0 + lc*4];
    }
    __syncthreads();
    #pragma unroll 4
    for (int k = 0; k < 64; k++) {
      float4 a4 = *(const float4*)&Ast[k][ty*4];
      float4 b4 = *(const float4*)&Bs[k][tx*4];
      acc[0][0] += a4.x*b4.x; acc[0][1] += a4.x*b4.y; acc[0][2] += a4.x*b4.z; acc[0][3] += a4.x*b4.w;
      acc[1][0] += a4.y*b4.x; acc[1][1] += a4.y*b4.y; acc[1][2] += a4.y*b4.z; acc[1][3] += a4.y*b4.w;
      acc[2][0] += a4.z*b4.x; acc[2][1] += a4.z*b4.y; acc[2][2] += a4.z*b4.z; acc[2][3] += a4.z*b4.w;
      acc[3][0] += a4.w*b4.x; acc[3][1] += a4.w*b4.y; acc[3][2] += a4.w*b4.z; acc[3][3] += a4.w*b4.w;
    }
    __syncthreads();
  }
  const float QS = 0.17677669529663687f * 1.4426950408889634f;
  float bb[4];
  #pragma unroll
  for (int j = 0; j < 4; j++) bb[j] = bias[m0 + tx*4 + j];
  int c0 = m0 + tx*4;
  if (c0 < 128) {
    int head = c0 >> 5, d = c0 & 31;
    #pragma unroll
    for (int i = 0; i < 4; i++) {
      int n = n0 + ty*4 + i;
      ushort4 s;
      s.x = f2b((acc[i][0]+bb[0])*QS); s.y = f2b((acc[i][1]+bb[1])*QS);
      s.z = f2b((acc[i][2]+bb[2])*QS); s.w = f2b((acc[i][3]+bb[3])*QS);
      *(ushort4*)&qb[((size_t)head*NN + n)*32 + d] = s;
    }
  } else if (c0 < 256) {
    int cc = c0 - 128;
    int head = cc >> 5, d = cc & 31;
    #pragma unroll
    for (int i = 0; i < 4; i++) {
      int n = n0 + ty*4 + i;
      ushort4 s;
      s.x = f2b(acc[i][0]+bb[0]); s.y = f2b(acc[i][1]+bb[1]);
      s.z = f2b(acc[i][2]+bb[2]); s.w = f2b(acc[i][3]+bb[3]);
      *(ushort4*)&kb[((size_t)head*NN + n)*32 + d] = s;
    }
  } else {
    int cc = c0 - 256;
    #pragma unroll
    for (int j = 0; j < 4; j++) {
      ushort4 s;
      s.x = f2b(acc[0][j]+bb[j]); s.y = f2b(acc[1][j]+bb[j]);
      s.z = f2b(acc[2][j]+bb[j]); s.w = f2b(acc[3][j]+bb[j]);
      *(ushort4*)&vt[(size_t)(cc + j)*NN + n0 + ty*4] = s;
    }
  }
}

// ---------------- MFMA flash attention, no max tracking (bounded scores) ----
// grid (KSPLIT, NN/64, 4 heads), block 256 (4 waves, 16 queries each).
__global__ __launch_bounds__(256) void mfma_attn_k(
    const u16* __restrict__ qb, const u16* __restrict__ kb,
    const u16* __restrict__ vt, float* __restrict__ opart,
    float* __restrict__ lpart) {
  __shared__ __align__(16) u16 pbuf[4][1024];

  const int w = threadIdx.x >> 6, lane = threadIdx.x & 63;
  const int g = lane >> 4, li = lane & 15;
  const int head = blockIdx.z;
  const int q0 = blockIdx.y * 64 + w * 16;
  const int j0 = blockIdx.x * KLEN;

  const bf16x8 qf = *reinterpret_cast<const bf16x8*>(
      qb + ((size_t)(head*NN) + q0 + li)*32 + g*8);

  f32x4 oacc0 = {0.f,0.f,0.f,0.f}, oacc1 = {0.f,0.f,0.f,0.f};
  const f32x4 zz = {0.f,0.f,0.f,0.f};
  float lsum = 0.f;
  char* pb = (char*)&pbuf[w][0];
  const int swz = (li & 7) << 4;

  for (int jt = j0; jt < j0 + KLEN; jt += 64) {
    f32x4 st[4];
    #pragma unroll
    for (int t = 0; t < 4; t++) {
      bf16x8 kf = *reinterpret_cast<const bf16x8*>(
          kb + ((size_t)(head*NN) + jt + t*16 + li)*32 + g*8);
      st[t] = __builtin_amdgcn_mfma_f32_16x16x32_bf16(kf, qf, zz, 0, 0, 0);
    }
    #pragma unroll
    for (int t = 0; t < 4; t++) {
      float p0 = exp2f(st[t][0]), p1 = exp2f(st[t][1]);
      float p2 = exp2f(st[t][2]), p3 = exp2f(st[t][3]);
      lsum += p0 + p1 + p2 + p3;
      uint2 wv;
      wv.x = pkbf2(p0, p1);
      wv.y = pkbf2(p2, p3);
      *reinterpret_cast<uint2*>(pb + ((li*128 + t*32 + g*8) ^ swz)) = wv;
    }
    #pragma unroll
    for (int c = 0; c < 2; c++) {
      bf16x8 pa = *reinterpret_cast<const bf16x8*>(pb + ((li*128 + c*64 + g*16) ^ swz));
      const u16* vrow = vt + ((size_t)(head*32 + li))*NN + jt + c*32 + g*8;
      bf16x8 vb0 = *reinterpret_cast<const bf16x8*>(vrow);
      bf16x8 vb1 = *reinterpret_cast<const bf16x8*>(vrow + (size_t)16*NN);
      oacc0 = __builtin_amdgcn_mfma_f32_16x16x32_bf16(pa, vb0, oacc0, 0, 0, 0);
      oacc1 = __builtin_amdgcn_mfma_f32_16x16x32_bf16(pa, vb1, oacc1, 0, 0, 0);
    }
  }
  lsum += __shfl_xor(lsum, 16);
  lsum += __shfl_xor(lsum, 32);

  size_t b = (size_t)(blockIdx.x*4 + head)*NN + q0;
  #pragma unroll
  for (int r = 0; r < 4; r++) {
    size_t ob = (b + 4*g + r)*32;
    opart[ob + li]      = oacc0[r];
    opart[ob + 16 + li] = oacc1[r];
  }
  if (lane < 16) lpart[b + lane] = lsum;
}

// combine KSPLIT partials -> attno[n, head*32+d]  (plain sums)
__global__ __launch_bounds__(256) void attn_merge_k(
    const float* __restrict__ opart, const float* __restrict__ lpart,
    float* __restrict__ attno) {
  int idx = blockIdx.x*256 + threadIdx.x;   // 4*NN*32
  int d = idx & 31;
  int n = (idx >> 5) & (NN-1);
  int head = idx >> 17;
  float L = 0.f, O = 0.f;
  #pragma unroll
  for (int s = 0; s < KSPLIT; s++) {
    size_t b = (size_t)(s*4+head)*NN + n;
    L += lpart[b];
    O += opart[b*32 + d];
  }
  attno[n*HH + head*32 + d] = O / L;
}

// ---------------- fused head MLP: per-graph block ----------------
__global__ __launch_bounds__(128) void head_k(
    const float* __restrict__ pooled,
    const float* __restrict__ Wr1, const float* __restrict__ br1,
    const float* __restrict__ Wr2, const float* __restrict__ br2,
    const float* __restrict__ Wc, const float* __restrict__ bc,
    float* __restrict__ out) {
  __shared__ float bufa[128], bufb[128];
  int g = blockIdx.x, c = threadIdx.x;
  bufa[c] = pooled[g*HH + c];
  __syncthreads();
  float acc = br1[c];
  #pragma unroll 8
  for (int k = 0; k < 128; k++) acc += bufa[k] * Wr1[k*128 + c];
  bufb[c] = fmaxf(acc, 0.f);
  __syncthreads();
  acc = br2[c];
  #pragma unroll 8
  for (int k = 0; k < 128; k++) acc += bufb[k] * Wr2[k*128 + c];
  bufa[c] = fmaxf(acc, 0.f);
  __syncthreads();
  if (c < 10) {
    acc = bc[c];
    #pragma unroll 8
    for (int k = 0; k < 128; k++) acc += bufa[k] * Wc[k*10 + c];
    out[g*10 + c] = acc;
  }
}

extern "C" void kernel_launch(void* const* d_in, const int* in_sizes, int n_in,
                              void* d_out, int out_size, void* d_ws, size_t ws_size,
                              hipStream_t stream) {
  const float* x      = (const float*)d_in[0];
  const float* lap    = (const float*)d_in[1];
  const float* rw     = (const float*)d_in[2];
  const int*   ei     = (const int*)d_in[3];
  const int*   batch  = (const int*)d_in[4];
  const float* Wp     = (const float*)d_in[5];
  const float* bp     = (const float*)d_in[6];
  const float* gin_W1 = (const float*)d_in[7];
  const float* gin_b1 = (const float*)d_in[8];
  const float* gin_W2 = (const float*)d_in[9];
  const float* gin_b2 = (const float*)d_in[10];
  const float* bn1_g  = (const float*)d_in[11];
  const float* bn1_b  = (const float*)d_in[12];
  const float* bn2_g  = (const float*)d_in[13];
  const float* bn2_b  = (const float*)d_in[14];
  const float* bn3_g  = (const float*)d_in[15];
  const float* bn3_b  = (const float*)d_in[16];
  const float* ain_w  = (const float*)d_in[17];
  const float* ain_b  = (const float*)d_in[18];
  const float* aout_w = (const float*)d_in[19];
  const float* aout_b = (const float*)d_in[20];
  const float* mlp_W1 = (const float*)d_in[21];
  const float* mlp_b1 = (const float*)d_in[22];
  const float* mlp_W2 = (const float*)d_in[23];
  const float* mlp_b2 = (const float*)d_in[24];
  const float* Wr1    = (const float*)d_in[25];
  const float* br1    = (const float*)d_in[26];
  const float* Wr2    = (const float*)d_in[27];
  const float* br2    = (const float*)d_in[28];
  const float* Wc     = (const float*)d_in[29];
  const float* bc     = (const float*)d_in[30];
  float* out = (float*)d_out;

  float* w = (float*)d_ws;
  float* h      = w + 0;          // 524288
  float* agg    = w + 524288;     // 524288  (stats1..3 follow contiguously)
  float* stats1 = w + 1048576;    // 256
  float* stats2 = w + 1048832;    // 256
  float* stats3 = w + 1049088;    // 256
  float* gtmp   = w + 1049344;    // 524288
  float* pre1   = w + 1573632;    // 524288
  float* pre2   = w + 2097920;    // 524288
  float* attno  = w + 2622208;    // 524288
  float* mlph   = w + 3146496;    // 1048576
  float* out3   = w + 4195072;    // 524288
  float* opart  = w + 4719360;    // 4194304 (KSPLIT=8)
  float* lpart  = w + 8913664;    // 131072
  float* pooled = w + 9044736;    // 8192
  float* aff    = w + 9052928;    // 512
  float* xcat   = w + 9053440;    // 524288
  float* wppad  = w + 9577728;    // 16384
  u16*   qb     = (u16*)(w + 9594112);  // 524288 u16
  u16*   kb     = (u16*)(w + 9856256);
  u16*   vt     = (u16*)(w + 10118400);

  hipMemsetAsync(pooled, 0, GG*HH*sizeof(float), stream);
  xcat_prep_k<<<NN*HH/256, 256, 0, stream>>>(x, lap, rw, xcat);
  wpad_prep_k<<<HH*HH/256, 256, 0, stream>>>(Wp, wppad);
  gemm64_k<<<dim3(64, 2), 256, 0, stream>>>(xcat, nullptr, wppad, bp, h, 128, 128, 0);

  for (int l = 0; l < 2; l++) {
    // zero agg + stats1..3 in one memset (contiguous)
    hipMemsetAsync(agg, 0, (524288 + 768)*sizeof(float), stream);
    edge_agg_k<<<EE/2, 256, 0, stream>>>(ei, h, agg);

    // ---- attention branch (depends only on h) ----
    gemm_qkv_k<<<dim3(64, 6), 256, 0, stream>>>(h, ain_w + l*HH*384, ain_b + l*384, qb, kb, vt);
    dim3 fgrid(KSPLIT, NN/64, 4);
    mfma_attn_k<<<fgrid, 256, 0, stream>>>(qb, kb, vt, opart, lpart);
    attn_merge_k<<<(4*NN*32)/256, 256, 0, stream>>>(opart, lpart, attno);

    // ---- GIN branch ----
    gemm64_k<<<dim3(64, 2), 256, 0, stream>>>(h, agg, gin_W1 + l*HH*HH, gin_b1 + l*HH, gtmp, 128, 128, 1);
    gemm64_resstat_k<<<dim3(64, 2), 256, 0, stream>>>(gtmp, gin_W2 + l*HH*HH, gin_b2 + l*HH, h, pre1, stats1);
    gemm64_resstat_k<<<dim3(64, 2), 256, 0, stream>>>(attno, aout_w + l*HH*HH, aout_b + l*HH, h, pre2, stats2);
    prep_aff_k<<<1, 256, 0, stream>>>(stats1, stats2, bn1_g + l*HH, bn1_b + l*HH,
                                      bn2_g + l*HH, bn2_b + l*HH, aff);

    // ---- combine + FFN ----
    gemm64_aff_k<<<dim3(64, 4), 256, 0, stream>>>(pre1, pre2, aff, mlp_W1 + l*HH*256, mlp_b1 + l*256, mlph);
    gemm64_s3_k<<<dim3(64, 2), 256, 0, stream>>>(mlph, mlp_W2 + l*256*HH, mlp_b2 + l*HH,
                                                 pre1, pre2, aff, out3, stats3);
    bn3_k<<<NN*HH/256, 256, 0, stream>>>(out3, stats3, bn3_g + l*HH, bn3_b + l*HH,
                                         h, batch, pooled, l == 1);
  }

  head_k<<<GG, 128, 0, stream>>>(pooled, Wr1, br1, Wr2, br2, Wc, bc, out);
}

// Round 6
// 240.466 us; speedup vs baseline: 6.6171x; 1.5803x over previous
//
#include <hip/hip_runtime.h>
#include <hip/hip_bf16.h>
#include <math.h>

#define NN 4096
#define HH 128
#define EE 65536
#define GG 64
#define KSPLIT 8
#define KLEN (NN / KSPLIT)

typedef unsigned short u16;
typedef unsigned int u32;
typedef __bf16 bf16x8 __attribute__((ext_vector_type(8)));
typedef float f32x4 __attribute__((ext_vector_type(4)));

__device__ inline u16 f2b(float f) {
  u32 u = __float_as_uint(f);
  u += 0x7FFFu + ((u >> 16) & 1u);
  return (u16)(u >> 16);
}
__device__ inline u32 pkbf2(float a, float b) {
  __hip_bfloat162 h = __float22bfloat162_rn(float2{a, b});
  u32 u; __builtin_memcpy(&u, &h, 4); return u;
}

// ---------------- one-shot weight transpose + bf16: Wt[m][k] = bf16(W[k][m]) ----
struct TDesc { const float* src; int Ks, K, M, off; };
struct TPack { TDesc d[13]; };

__global__ __launch_bounds__(256) void transpose_all_k(TPack P, u16* __restrict__ dst) {
  int idx = blockIdx.x * 256 + threadIdx.x;
  for (int i = 0; i < 13; i++) {
    int sz = P.d[i].K * P.d[i].M;
    if (idx < sz) {
      int m = idx / P.d[i].K;
      int k = idx - m * P.d[i].K;
      float v = (k < P.d[i].Ks) ? P.d[i].src[(size_t)k * P.d[i].M + m] : 0.f;
      dst[P.d[i].off + idx] = f2b(v);
      return;
    }
    idx -= sz;
  }
}

__global__ __launch_bounds__(512) void idaff_k(float* __restrict__ a) {
  int i = threadIdx.x;
  a[i] = (i < 128 || (i >= 256 && i < 384)) ? 1.f : 0.f;
}

// ---------------- concat+pad prep for input projection ----------------
__global__ __launch_bounds__(256) void xcat_prep_k(
    const float* __restrict__ x, const float* __restrict__ lap,
    const float* __restrict__ rw, float* __restrict__ xcat) {
  int idx = blockIdx.x*256 + threadIdx.x;   // 4096*128
  int n = idx >> 7, c = idx & 127;
  float v = 0.f;
  if (c < 64)      v = x[n*64 + c];
  else if (c < 72) v = lap[n*8 + c - 64];
  else if (c < 88) v = rw[n*16 + c - 72];
  xcat[idx] = v;
}

// ---------------- edge scatter-add: agg[dst] += h[src] ----------------
__global__ __launch_bounds__(256) void edge_agg_k(
    const int* __restrict__ ei, const float* __restrict__ h, float* agg) {
  int e = blockIdx.x*2 + (threadIdx.x >> 7);
  int c = threadIdx.x & 127;
  int s = ei[e], d = ei[EE + e];
  atomicAdd(&agg[d*HH+c], h[s*HH+c]);
}

// ---------------- bf16 MFMA GEMM, tile 32(n) x 64(m) x K, 256 thr (4 waves) ----
// EPI: 0 plain(+relu)   1 resstat (v=acc+bias+res; stats)   2 aff-staged A (+relu)
//      3 s3 (v=acc+bias+aff(res)+aff2(res2); stats)         4 qkv epilogue
template <int EPI, int RELU>
__global__ __launch_bounds__(256) void mgemm_k(
    const float* __restrict__ A, const float* __restrict__ A2,
    const float* __restrict__ aff, const u16* __restrict__ Bt,
    const float* __restrict__ bias, const float* __restrict__ bias2,
    float* __restrict__ C, const float* __restrict__ res,
    const float* __restrict__ res2, float* __restrict__ stats,
    u16* __restrict__ qb, u16* __restrict__ kb, u16* __restrict__ vt,
    int K, int M) {
  __shared__ __align__(16) u16 As[32*64];   // [row][k], XOR-swizzled
  __shared__ __align__(16) u16 Bs[64*64];   // [col][k], XOR-swizzled
  const int tid = threadIdx.x;
  const int n0 = blockIdx.x * 32, m0 = blockIdx.y * 64;
  const int w = tid >> 6, lane = tid & 63;
  const int g = lane >> 4, li = lane & 15;
  const int wr = w >> 1, wc = w & 1;

  f32x4 acc0 = {0,0,0,0}, acc1 = {0,0,0,0};
  const int arow = tid >> 3, akseg = (tid & 7) * 8;
  const int bcol = tid >> 2, bkseg = (tid & 3) * 16;
  char* Ab = (char*)As;
  char* Bb = (char*)Bs;

  for (int k0 = 0; k0 < K; k0 += 64) {
    {  // stage A fp32 -> bf16 (optionally affine-combined with A2)
      const float* ap = A + (size_t)(n0 + arow) * K + k0 + akseg;
      float4 a0 = *(const float4*)ap, a1 = *(const float4*)(ap + 4);
      if (EPI == 2) {
        const float* p2 = A2 + (size_t)(n0 + arow) * K + k0 + akseg;
        float4 c0 = *(const float4*)p2, c1 = *(const float4*)(p2 + 4);
        const float* af = aff + k0 + akseg;
        float4 s1a = *(const float4*)af,         s1b = *(const float4*)(af + 4);
        float4 t1a = *(const float4*)(af + 128), t1b = *(const float4*)(af + 132);
        float4 s2a = *(const float4*)(af + 256), s2b = *(const float4*)(af + 260);
        float4 t2a = *(const float4*)(af + 384), t2b = *(const float4*)(af + 388);
        a0.x = a0.x*s1a.x + t1a.x + c0.x*s2a.x + t2a.x;
        a0.y = a0.y*s1a.y + t1a.y + c0.y*s2a.y + t2a.y;
        a0.z = a0.z*s1a.z + t1a.z + c0.z*s2a.z + t2a.z;
        a0.w = a0.w*s1a.w + t1a.w + c0.w*s2a.w + t2a.w;
        a1.x = a1.x*s1b.x + t1b.x + c1.x*s2b.x + t2b.x;
        a1.y = a1.y*s1b.y + t1b.y + c1.y*s2b.y + t2b.y;
        a1.z = a1.z*s1b.z + t1b.z + c1.z*s2b.z + t2b.z;
        a1.w = a1.w*s1b.w + t1b.w + c1.w*s2b.w + t2b.w;
      }
      u16 t8[8] = {f2b(a0.x), f2b(a0.y), f2b(a0.z), f2b(a0.w),
                   f2b(a1.x), f2b(a1.y), f2b(a1.z), f2b(a1.w)};
      *(uint4*)(Ab + ((arow*128 + akseg*2) ^ ((arow & 7) << 4))) = *(uint4*)t8;
    }
    {  // stage B (already bf16, [m][k])
      const u16* bp = Bt + (size_t)(m0 + bcol) * K + k0 + bkseg;
      uint4 b0 = *(const uint4*)bp;
      uint4 b1 = *(const uint4*)(bp + 8);
      int ba = bcol*128 + bkseg*2;
      int sw = (bcol & 7) << 4;
      *(uint4*)(Bb + (ba ^ sw)) = b0;
      *(uint4*)(Bb + ((ba + 16) ^ sw)) = b1;
    }
    __syncthreads();
    int row = wr*16 + li;
    int colAl = wc*32 + li, colBl = colAl + 16;
    #pragma unroll
    for (int ck = 0; ck < 2; ck++) {
      bf16x8 af = *(const bf16x8*)(Ab + ((row*128 + ck*64 + g*16) ^ ((row & 7) << 4)));
      bf16x8 bf0 = *(const bf16x8*)(Bb + ((colAl*128 + ck*64 + g*16) ^ ((colAl & 7) << 4)));
      bf16x8 bf1 = *(const bf16x8*)(Bb + ((colBl*128 + ck*64 + g*16) ^ ((colBl & 7) << 4)));
      acc0 = __builtin_amdgcn_mfma_f32_16x16x32_bf16(af, bf0, acc0, 0, 0, 0);
      acc1 = __builtin_amdgcn_mfma_f32_16x16x32_bf16(af, bf1, acc1, 0, 0, 0);
    }
    __syncthreads();
  }

  const int colA = m0 + wc*32 + li, colB = colA + 16;
  const int colAl = wc*32 + li, colBl = colAl + 16;
  const int rbase = n0 + wr*16 + 4*g;

  if (EPI == 0 || EPI == 2) {
    float b0 = bias[colA], b1 = bias[colB];
    #pragma unroll
    for (int r = 0; r < 4; r++) {
      float v0 = acc0[r] + b0, v1 = acc1[r] + b1;
      if (RELU) { v0 = fmaxf(v0, 0.f); v1 = fmaxf(v1, 0.f); }
      C[(size_t)(rbase + r) * M + colA] = v0;
      C[(size_t)(rbase + r) * M + colB] = v1;
    }
  } else if (EPI == 1 || EPI == 3) {
    float b0 = bias[colA], b1 = bias[colB];
    float s0 = 0, q0 = 0, s1 = 0, q1 = 0;
    #pragma unroll
    for (int r = 0; r < 4; r++) {
      int rw2 = rbase + r;
      float v0, v1;
      if (EPI == 1) {
        v0 = acc0[r] + b0 + res[(size_t)rw2 * 128 + colA];
        v1 = acc1[r] + b1 + res[(size_t)rw2 * 128 + colB];
      } else {
        v0 = acc0[r] + b0 + res[(size_t)rw2*128 + colA]*aff[colA] + aff[128+colA]
                          + res2[(size_t)rw2*128 + colA]*aff[256+colA] + aff[384+colA];
        v1 = acc1[r] + b1 + res[(size_t)rw2*128 + colB]*aff[colB] + aff[128+colB]
                          + res2[(size_t)rw2*128 + colB]*aff[256+colB] + aff[384+colB];
      }
      C[(size_t)rw2 * M + colA] = v0;
      C[(size_t)rw2 * M + colB] = v1;
      s0 += v0; q0 += v0*v0; s1 += v1; q1 += v1*v1;
    }
    // sum over the 4 row-groups (g) of this wave: lanes li,li+16,li+32,li+48
    s0 += __shfl_xor(s0, 16); s0 += __shfl_xor(s0, 32);
    q0 += __shfl_xor(q0, 16); q0 += __shfl_xor(q0, 32);
    s1 += __shfl_xor(s1, 16); s1 += __shfl_xor(s1, 32);
    q1 += __shfl_xor(q1, 16); q1 += __shfl_xor(q1, 32);
    // scratch layout: sum plane sred[wr*64 + col], sq plane sred[128 + wr*64 + col]
    // wave (wr,wc) owns cols [wc*32, wc*32+32) -> no overlap, full coverage.
    float* sred = (float*)As;
    if (lane < 16) {
      sred[wr*64 + colAl] = s0;  sred[128 + wr*64 + colAl] = q0;
      sred[wr*64 + colBl] = s1;  sred[128 + wr*64 + colBl] = q1;
    }
    __syncthreads();
    if (tid < 128) {
      int c = tid & 63, isq = tid >> 6;
      float v = sred[isq*128 + c] + sred[isq*128 + 64 + c];
      atomicAdd(&stats[isq*128 + m0 + c], v);
    }
  } else {  // EPI == 4: qkv epilogue
    const float QS = 0.17677669529663687f * 1.4426950408889634f;
    auto doq = [&](int col, f32x4 acc, float bb) {
      if (col < 128) {
        int hd = col >> 5, d = col & 31;
        #pragma unroll
        for (int r = 0; r < 4; r++)
          qb[((size_t)hd*NN + rbase + r)*32 + d] = f2b((acc[r] + bb) * QS);
      } else if (col < 256) {
        int hd = (col - 128) >> 5, d = col & 31;
        #pragma unroll
        for (int r = 0; r < 4; r++)
          kb[((size_t)hd*NN + rbase + r)*32 + d] = f2b(acc[r] + bb);
      } else {
        #pragma unroll
        for (int r = 0; r < 4; r++)
          vt[(size_t)(col - 256)*NN + rbase + r] = f2b(acc[r] + bb);
      }
    };
    doq(colA, acc0, bias[colA]);
    doq(colB, acc1, bias[colB]);
  }
}

// ---- affine params from stats: s = rsqrt(var+eps)*gamma, t = beta - mean*s
__global__ __launch_bounds__(256) void prep_aff_k(
    const float* __restrict__ stats1, const float* __restrict__ stats2,
    const float* __restrict__ g1, const float* __restrict__ b1,
    const float* __restrict__ g2, const float* __restrict__ b2,
    float* __restrict__ aff) {
  int c = threadIdx.x;
  int cc = c & 127;
  const float* st = (c < 128) ? stats1 : stats2;
  const float* gg = (c < 128) ? g1 : g2;
  const float* bb = (c < 128) ? b1 : b2;
  float mean = st[cc] * (1.f/NN);
  float var  = st[128+cc] * (1.f/NN) - mean*mean;
  float s = rsqrtf(var + 1e-5f) * gg[cc];
  int base = (c < 128) ? 0 : 256;
  aff[base + cc]       = s;
  aff[base + 128 + cc] = bb[cc] - mean*s;
}

// ---- BN3 apply (+relu) -> h; optionally pool instead of writing h
__global__ __launch_bounds__(256) void bn3_k(
    const float* __restrict__ out3, const float* __restrict__ stats,
    const float* __restrict__ gamma, const float* __restrict__ beta,
    float* __restrict__ h, const int* __restrict__ batch,
    float* __restrict__ pooled, int dopool) {
  int idx = blockIdx.x*256 + threadIdx.x;
  int c = idx & 127;
  float mean = stats[c] * (1.f/NN);
  float var  = stats[128+c] * (1.f/NN) - mean*mean;
  float rs = rsqrtf(var + 1e-5f);
  float r = fmaxf((out3[idx] - mean) * rs * gamma[c] + beta[c], 0.f);
  if (dopool) atomicAdd(&pooled[batch[idx >> 7]*HH + c], r);
  else        h[idx] = r;
}

// ---------------- MFMA flash attention, LDS-staged K/V (double-buffered) -----
// grid (KSPLIT, NN/64, 4 heads), block 256 (4 waves, 16 queries each).
__global__ __launch_bounds__(256) void mfma_attn_k(
    const u16* __restrict__ qb, const u16* __restrict__ kb,
    const u16* __restrict__ vt, float* __restrict__ opart,
    float* __restrict__ lpart) {
  __shared__ __align__(16) u16 kbuf[2][2048];   // [64 keys][32 d] linear
  __shared__ __align__(16) u16 vbuf[2][2048];   // [32 d][64 keys] src-swizzled
  __shared__ __align__(16) u16 pbuf[4][1024];

  const int tid = threadIdx.x;
  const int w = tid >> 6, lane = tid & 63;
  const int g = lane >> 4, li = lane & 15;
  const int head = blockIdx.z;
  const int q0 = blockIdx.y * 64 + w * 16;
  const int j0 = blockIdx.x * KLEN;

  const bf16x8 qf = *reinterpret_cast<const bf16x8*>(
      qb + ((size_t)(head*NN) + q0 + li)*32 + g*8);

  const int vd = tid >> 3;                       // d row 0..31
  const int vcs = (tid & 7) ^ (vd & 7);          // source-swizzled col seg
  const u16* kpan = kb + (size_t)head*NN*32;
  const u16* vrow_g = vt + (size_t)(head*32 + vd)*NN;

  f32x4 oacc0 = {0,0,0,0}, oacc1 = {0,0,0,0};
  const f32x4 zz = {0,0,0,0};
  float lsum = 0.f;
  char* pb = (char*)&pbuf[w][0];
  const int swz = (li & 7) << 4;

  {  // prologue: stage step 0 into buf 0
    uint4 kv = *(const uint4*)(kpan + (size_t)j0*32 + tid*8);
    uint4 vv = *(const uint4*)(vrow_g + j0 + vcs*8);
    *((uint4*)kbuf[0] + tid) = kv;
    *((uint4*)vbuf[0] + tid) = vv;
  }
  __syncthreads();

  const int NSTEP = KLEN / 64;
  int cur = 0;
  for (int s = 0; s < NSTEP; s++) {
    int jt = j0 + s*64;
    bool pf = (s + 1 < NSTEP);
    uint4 kv = {0,0,0,0}, vv = {0,0,0,0};
    if (pf) {  // T14: issue next-tile loads early, write after compute
      kv = *(const uint4*)(kpan + (size_t)(jt + 64)*32 + tid*8);
      vv = *(const uint4*)(vrow_g + jt + 64 + vcs*8);
    }
    f32x4 st[4];
    #pragma unroll
    for (int t = 0; t < 4; t++) {
      bf16x8 kf = *(const bf16x8*)&kbuf[cur][(t*16 + li)*32 + g*8];
      st[t] = __builtin_amdgcn_mfma_f32_16x16x32_bf16(kf, qf, zz, 0, 0, 0);
    }
    #pragma unroll
    for (int t = 0; t < 4; t++) {
      float p0 = exp2f(st[t][0]), p1 = exp2f(st[t][1]);
      float p2 = exp2f(st[t][2]), p3 = exp2f(st[t][3]);
      lsum += p0 + p1 + p2 + p3;
      uint2 wv2;
      wv2.x = pkbf2(p0, p1);
      wv2.y = pkbf2(p2, p3);
      *(uint2*)(pb + ((li*128 + t*32 + g*8) ^ swz)) = wv2;
    }
    #pragma unroll
    for (int c = 0; c < 2; c++) {
      bf16x8 pa = *(const bf16x8*)(pb + ((li*128 + c*64 + g*16) ^ swz));
      int vs = ((c*4 + g) ^ (li & 7)) << 4;
      bf16x8 vb0 = *(const bf16x8*)((char*)vbuf[cur] + li*128 + vs);
      bf16x8 vb1 = *(const bf16x8*)((char*)vbuf[cur] + (16 + li)*128 + vs);
      oacc0 = __builtin_amdgcn_mfma_f32_16x16x32_bf16(pa, vb0, oacc0, 0, 0, 0);
      oacc1 = __builtin_amdgcn_mfma_f32_16x16x32_bf16(pa, vb1, oacc1, 0, 0, 0);
    }
    if (pf) {
      *((uint4*)kbuf[cur ^ 1] + tid) = kv;
      *((uint4*)vbuf[cur ^ 1] + tid) = vv;
    }
    __syncthreads();
    cur ^= 1;
  }
  lsum += __shfl_xor(lsum, 16);
  lsum += __shfl_xor(lsum, 32);

  size_t b = (size_t)(blockIdx.x*4 + head)*NN + q0;
  #pragma unroll
  for (int r = 0; r < 4; r++) {
    size_t ob = (b + 4*g + r)*32;
    opart[ob + li]      = oacc0[r];
    opart[ob + 16 + li] = oacc1[r];
  }
  if (lane < 16) lpart[b + lane] = lsum;
}

// combine KSPLIT partials -> attno[n, head*32+d]  (plain sums)
__global__ __launch_bounds__(256) void attn_merge_k(
    const float* __restrict__ opart, const float* __restrict__ lpart,
    float* __restrict__ attno) {
  int idx = blockIdx.x*256 + threadIdx.x;   // 4*NN*32
  int d = idx & 31;
  int n = (idx >> 5) & (NN-1);
  int head = idx >> 17;
  float L = 0.f, O = 0.f;
  #pragma unroll
  for (int s = 0; s < KSPLIT; s++) {
    size_t b = (size_t)(s*4+head)*NN + n;
    L += lpart[b];
    O += opart[b*32 + d];
  }
  attno[n*HH + head*32 + d] = O / L;
}

// ---------------- fused head MLP: per-graph block ----------------
__global__ __launch_bounds__(128) void head_k(
    const float* __restrict__ pooled,
    const float* __restrict__ Wr1, const float* __restrict__ br1,
    const float* __restrict__ Wr2, const float* __restrict__ br2,
    const float* __restrict__ Wc, const float* __restrict__ bc,
    float* __restrict__ out) {
  __shared__ float bufa[128], bufb[128];
  int g = blockIdx.x, c = threadIdx.x;
  bufa[c] = pooled[g*HH + c];
  __syncthreads();
  float acc = br1[c];
  #pragma unroll 8
  for (int k = 0; k < 128; k++) acc += bufa[k] * Wr1[k*128 + c];
  bufb[c] = fmaxf(acc, 0.f);
  __syncthreads();
  acc = br2[c];
  #pragma unroll 8
  for (int k = 0; k < 128; k++) acc += bufb[k] * Wr2[k*128 + c];
  bufa[c] = fmaxf(acc, 0.f);
  __syncthreads();
  if (c < 10) {
    acc = bc[c];
    #pragma unroll 8
    for (int k = 0; k < 128; k++) acc += bufa[k] * Wc[k*10 + c];
    out[g*10 + c] = acc;
  }
}

extern "C" void kernel_launch(void* const* d_in, const int* in_sizes, int n_in,
                              void* d_out, int out_size, void* d_ws, size_t ws_size,
                              hipStream_t stream) {
  const float* x      = (const float*)d_in[0];
  const float* lap    = (const float*)d_in[1];
  const float* rw     = (const float*)d_in[2];
  const int*   ei     = (const int*)d_in[3];
  const int*   batch  = (const int*)d_in[4];
  const float* Wp     = (const float*)d_in[5];
  const float* bp     = (const float*)d_in[6];
  const float* gin_W1 = (const float*)d_in[7];
  const float* gin_b1 = (const float*)d_in[8];
  const float* gin_W2 = (const float*)d_in[9];
  const float* gin_b2 = (const float*)d_in[10];
  const float* bn1_g  = (const float*)d_in[11];
  const float* bn1_b  = (const float*)d_in[12];
  const float* bn2_g  = (const float*)d_in[13];
  const float* bn2_b  = (const float*)d_in[14];
  const float* bn3_g  = (const float*)d_in[15];
  const float* bn3_b  = (const float*)d_in[16];
  const float* ain_w  = (const float*)d_in[17];
  const float* ain_b  = (const float*)d_in[18];
  const float* aout_w = (const float*)d_in[19];
  const float* aout_b = (const float*)d_in[20];
  const float* mlp_W1 = (const float*)d_in[21];
  const float* mlp_b1 = (const float*)d_in[22];
  const float* mlp_W2 = (const float*)d_in[23];
  const float* mlp_b2 = (const float*)d_in[24];
  const float* Wr1    = (const float*)d_in[25];
  const float* br1    = (const float*)d_in[26];
  const float* Wr2    = (const float*)d_in[27];
  const float* br2    = (const float*)d_in[28];
  const float* Wc     = (const float*)d_in[29];
  const float* bc     = (const float*)d_in[30];
  float* out = (float*)d_out;

  float* w = (float*)d_ws;
  float* h      = w + 0;          // 524288
  float* agg    = w + 524288;     // 524288 (stats follow contiguously)
  float* stats1 = w + 1048576;    // 256
  float* stats2 = w + 1048832;    // 256
  float* stats3 = w + 1049088;    // 256
  float* gtmp   = w + 1049344;    // 524288
  float* pre1   = w + 1573632;    // 524288
  float* pre2   = w + 2097920;    // 524288
  float* attno  = w + 2622208;    // 524288
  float* mlph   = w + 3146496;    // 1048576
  float* out3   = w + 4195072;    // 524288
  float* opart  = w + 4719360;    // 4194304
  float* lpart  = w + 8913664;    // 131072
  float* pooled = w + 9044736;    // 8192
  float* aff    = w + 9052928;    // 512
  float* idaff  = w + 9053440;    // 512
  float* xcat   = w + 9053952;    // 524288
  u16*   wts    = (u16*)(w + 9578240);   // 344064 u16
  u16*   qb     = (u16*)(w + 9750272);
  u16*   kb     = (u16*)(w + 10012416);
  u16*   vt     = (u16*)(w + 10274560);

  u16* wpt = wts;
  u16 *qkvWt[2], *g1t[2], *g2t[2], *aot[2], *m1t[2], *m2t[2];
  {
    int off = 16384;
    for (int l = 0; l < 2; l++) {
      qkvWt[l] = wts + off; off += 384*128;
      g1t[l]   = wts + off; off += 128*128;
      g2t[l]   = wts + off; off += 128*128;
      aot[l]   = wts + off; off += 128*128;
      m1t[l]   = wts + off; off += 256*128;
      m2t[l]   = wts + off; off += 128*256;
    }
  }
  TPack tp;
  {
    int ti = 0, toff = 0;
    auto addm = [&](const float* s, int Ks, int Kd, int Md) {
      tp.d[ti].src = s; tp.d[ti].Ks = Ks; tp.d[ti].K = Kd; tp.d[ti].M = Md;
      tp.d[ti].off = toff; toff += Kd * Md; ti++;
    };
    addm(Wp, 88, 128, 128);
    for (int l = 0; l < 2; l++) {
      addm(ain_w + l*HH*384, 128, 128, 384);
      addm(gin_W1 + l*HH*HH, 128, 128, 128);
      addm(gin_W2 + l*HH*HH, 128, 128, 128);
      addm(aout_w + l*HH*HH, 128, 128, 128);
      addm(mlp_W1 + l*HH*256, 128, 128, 256);
      addm(mlp_W2 + l*256*HH, 256, 256, 128);
    }
  }

  hipMemsetAsync(pooled, 0, GG*HH*sizeof(float), stream);
  transpose_all_k<<<1344, 256, 0, stream>>>(tp, wts);
  idaff_k<<<1, 512, 0, stream>>>(idaff);
  xcat_prep_k<<<NN*HH/256, 256, 0, stream>>>(x, lap, rw, xcat);
  mgemm_k<0,0><<<dim3(128,2), 256, 0, stream>>>(
      xcat, nullptr, nullptr, wpt, bp, nullptr, h,
      nullptr, nullptr, nullptr, nullptr, nullptr, nullptr, 128, 128);

  for (int l = 0; l < 2; l++) {
    hipMemsetAsync(agg, 0, (524288 + 768)*sizeof(float), stream);
    edge_agg_k<<<EE/2, 256, 0, stream>>>(ei, h, agg);

    // ---- attention branch ----
    mgemm_k<4,0><<<dim3(128,6), 256, 0, stream>>>(
        h, nullptr, nullptr, qkvWt[l], ain_b + l*384, nullptr, nullptr,
        nullptr, nullptr, nullptr, qb, kb, vt, 128, 384);
    mfma_attn_k<<<dim3(KSPLIT,64,4), 256, 0, stream>>>(qb, kb, vt, opart, lpart);
    attn_merge_k<<<(4*NN*32)/256, 256, 0, stream>>>(opart, lpart, attno);

    // ---- GIN branch ----
    mgemm_k<2,1><<<dim3(128,2), 256, 0, stream>>>(
        h, agg, idaff, g1t[l], gin_b1 + l*HH, nullptr, gtmp,
        nullptr, nullptr, nullptr, nullptr, nullptr, nullptr, 128, 128);
    mgemm_k<1,0><<<dim3(128,2), 256, 0, stream>>>(
        gtmp, nullptr, nullptr, g2t[l], gin_b2 + l*HH, nullptr, pre1,
        h, nullptr, stats1, nullptr, nullptr, nullptr, 128, 128);
    mgemm_k<1,0><<<dim3(128,2), 256, 0, stream>>>(
        attno, nullptr, nullptr, aot[l], aout_b + l*HH, nullptr, pre2,
        h, nullptr, stats2, nullptr, nullptr, nullptr, 128, 128);
    prep_aff_k<<<1, 256, 0, stream>>>(stats1, stats2, bn1_g + l*HH, bn1_b + l*HH,
                                      bn2_g + l*HH, bn2_b + l*HH, aff);

    // ---- combine + FFN ----
    mgemm_k<2,1><<<dim3(128,4), 256, 0, stream>>>(
        pre1, pre2, aff, m1t[l], mlp_b1 + l*256, nullptr, mlph,
        nullptr, nullptr, nullptr, nullptr, nullptr, nullptr, 128, 256);
    mgemm_k<3,0><<<dim3(128,2), 256, 0, stream>>>(
        mlph, nullptr, aff, m2t[l], mlp_b2 + l*HH, nullptr, out3,
        pre1, pre2, stats3, nullptr, nullptr, nullptr, 256, 128);
    bn3_k<<<NN*HH/256, 256, 0, stream>>>(out3, stats3, bn3_g + l*HH, bn3_b + l*HH,
                                         h, batch, pooled, l == 1);
  }

  head_k<<<GG, 128, 0, stream>>>(pooled, Wr1, br1, Wr2, br2, Wc, bc, out);
}

// Round 7
// 205.142 us; speedup vs baseline: 7.7565x; 1.1722x over previous
//
#include <hip/hip_runtime.h>
#include <hip/hip_bf16.h>
#include <math.h>

#define NN 4096
#define HH 128
#define EE 65536
#define GG 64
#define KSPLIT 8
#define KLEN (NN / KSPLIT)

typedef unsigned short u16;
typedef unsigned int u32;
typedef __bf16 bf16x8 __attribute__((ext_vector_type(8)));
typedef float f32x4 __attribute__((ext_vector_type(4)));

__device__ inline u16 f2b(float f) {
  u32 u = __float_as_uint(f);
  u += 0x7FFFu + ((u >> 16) & 1u);
  return (u16)(u >> 16);
}
__device__ inline u32 pkbf2(float a, float b) {
  __hip_bfloat162 h = __float22bfloat162_rn(float2{a, b});
  u32 u; __builtin_memcpy(&u, &h, 4); return u;
}

// ---------------- one-shot weight transpose + bf16: Wt[m][k] = bf16(W[k][m]) ----
struct TDesc { const float* src; int Ks, K, M, off; };
struct TPack { TDesc d[13]; };

__global__ __launch_bounds__(256) void transpose_all_k(TPack P, u16* __restrict__ dst) {
  int idx = blockIdx.x * 256 + threadIdx.x;
  for (int i = 0; i < 13; i++) {
    int sz = P.d[i].K * P.d[i].M;
    if (idx < sz) {
      int m = idx / P.d[i].K;
      int k = idx - m * P.d[i].K;
      float v = (k < P.d[i].Ks) ? P.d[i].src[(size_t)k * P.d[i].M + m] : 0.f;
      dst[P.d[i].off + idx] = f2b(v);
      return;
    }
    idx -= sz;
  }
}

// ---------------- CSR build (once per call; edges are layer-invariant) --------
__global__ __launch_bounds__(256) void count_k(const int* __restrict__ ei, int* cnt) {
  int e = blockIdx.x*256 + threadIdx.x;
  atomicAdd(&cnt[ei[EE + e]], 1);
}

__global__ __launch_bounds__(256) void scan_k(const int* __restrict__ cnt,
    int* __restrict__ rowptr, int* __restrict__ cursor) {
  __shared__ int tot[256];
  int t = threadIdx.x;
  int base = t * 16;
  int loc[16]; int s = 0;
  #pragma unroll
  for (int i = 0; i < 16; i++) { loc[i] = s; s += cnt[base + i]; }
  tot[t] = s;
  __syncthreads();
  for (int off = 1; off < 256; off <<= 1) {
    int v = (t >= off) ? tot[t - off] : 0;
    __syncthreads();
    tot[t] += v;
    __syncthreads();
  }
  int excl = (t == 0) ? 0 : tot[t - 1];
  #pragma unroll
  for (int i = 0; i < 16; i++) {
    int p = excl + loc[i];
    rowptr[base + i] = p; cursor[base + i] = p;
  }
  if (t == 255) rowptr[NN] = excl + s;
}

__global__ __launch_bounds__(256) void scatter_k(const int* __restrict__ ei,
    int* cursor, int* __restrict__ elist) {
  int e = blockIdx.x*256 + threadIdx.x;
  int d = ei[EE + e];
  int p = atomicAdd(&cursor[d], 1);
  elist[p] = ei[e];
}

// per-layer gather-sum: agg[d] = sum_{e: dst=d} h[src_e]   (no atomics)
__global__ __launch_bounds__(256) void aggcsr_k(const int* __restrict__ rowptr,
    const int* __restrict__ elist, const float* __restrict__ h,
    float* __restrict__ agg) {
  int d = blockIdx.x*2 + (threadIdx.x >> 7);
  int c = threadIdx.x & 127;
  int beg = rowptr[d], end = rowptr[d + 1];
  float acc = 0.f;
  for (int j = beg; j < end; j++)
    acc += h[(size_t)elist[j]*HH + c];
  agg[(size_t)d*HH + c] = acc;
}

// ---------------- bf16 MFMA GEMM, tile 32(n) x 64(m), 256 thr (4 waves) -------
// ASTAGE: 0 A only | 1 A+A2 | 2 BN1(A)+BN2(A2) from stats (ffn1) | 3 inline
//         KSPLIT-merge of opart/lpart (attn-out) | 4 inline [x,lap,rw] concat
// EPI: 0 plain(+RELU) | 1 v=acc+bias+res, +stats | 3 v=acc+bias+BN1(res)+BN2(res2),
//      +stats (ffn2) | 4 qkv bf16 epilogue
template <int ASTAGE, int EPI, int RELU>
__global__ __launch_bounds__(256) void mgemm_k(
    const float* __restrict__ A, const float* __restrict__ A2,
    const float* __restrict__ A3, const u16* __restrict__ Bt,
    const float* __restrict__ bias, float* __restrict__ C,
    const float* __restrict__ res, const float* __restrict__ res2,
    float* __restrict__ stats, const float* __restrict__ sbase,
    const float* __restrict__ pg1, const float* __restrict__ pb1,
    const float* __restrict__ pg2, const float* __restrict__ pb2,
    const float* __restrict__ opart, const float* __restrict__ lpart,
    u16* __restrict__ qb, u16* __restrict__ kb, u16* __restrict__ vt,
    int K, int M) {
  __shared__ __align__(16) u16 As[32*64];   // [row][k], XOR-swizzled
  __shared__ __align__(16) u16 Bs[64*64];   // [col][k], XOR-swizzled
  __shared__ __align__(16) float affs[512];
  const int tid = threadIdx.x;
  const int n0 = blockIdx.x * 32, m0 = blockIdx.y * 64;
  const int w = tid >> 6, lane = tid & 63;
  const int g = lane >> 4, li = lane & 15;
  const int wr = w >> 1, wc = w & 1;

  if (ASTAGE == 2) {  // affine params once per block into LDS
    int plane = tid >> 7, cc = tid & 127;
    const float* st = sbase + plane*256;
    const float* gg = plane ? pg2 : pg1;
    const float* bb = plane ? pb2 : pb1;
    float mean = st[cc] * (1.f/NN);
    float var  = st[128+cc] * (1.f/NN) - mean*mean;
    float s = rsqrtf(var + 1e-5f) * gg[cc];
    affs[plane*256 + cc]       = s;
    affs[plane*256 + 128 + cc] = bb[cc] - mean*s;
    __syncthreads();
  }

  f32x4 acc0 = {0,0,0,0}, acc1 = {0,0,0,0};
  const int arow = tid >> 3, akseg = (tid & 7) * 8;
  const int bcol = tid >> 2, bkseg = (tid & 3) * 16;
  char* Ab = (char*)As;
  char* Bb = (char*)Bs;

  for (int k0 = 0; k0 < K; k0 += 64) {
    {  // stage A fp32 -> bf16
      float4 a0 = {0,0,0,0}, a1 = {0,0,0,0};
      if (ASTAGE == 4) {
        int n = n0 + arow;
        if (k0 == 0) {
          a0 = *(const float4*)&A[(size_t)n*64 + akseg];
          a1 = *(const float4*)&A[(size_t)n*64 + akseg + 4];
        } else {
          if (akseg == 0)       { a0 = *(const float4*)&A2[(size_t)n*8];
                                  a1 = *(const float4*)&A2[(size_t)n*8 + 4]; }
          else if (akseg == 8)  { a0 = *(const float4*)&A3[(size_t)n*16];
                                  a1 = *(const float4*)&A3[(size_t)n*16 + 4]; }
          else if (akseg == 16) { a0 = *(const float4*)&A3[(size_t)n*16 + 8];
                                  a1 = *(const float4*)&A3[(size_t)n*16 + 12]; }
        }
      } else if (ASTAGE == 3) {
        int n = n0 + arow, c = k0 + akseg;
        int head = c >> 5, d0 = c & 31;
        float4 o0 = {0,0,0,0}, o1 = {0,0,0,0}; float L = 0.f;
        #pragma unroll
        for (int s = 0; s < KSPLIT; s++) {
          const float* ob = opart + ((size_t)(s*4+head)*NN + n)*32 + d0;
          float4 x0 = *(const float4*)ob, x1 = *(const float4*)(ob + 4);
          o0.x += x0.x; o0.y += x0.y; o0.z += x0.z; o0.w += x0.w;
          o1.x += x1.x; o1.y += x1.y; o1.z += x1.z; o1.w += x1.w;
          L += lpart[(size_t)(s*4+head)*NN + n];
        }
        float inv = 1.f / L;
        a0 = make_float4(o0.x*inv, o0.y*inv, o0.z*inv, o0.w*inv);
        a1 = make_float4(o1.x*inv, o1.y*inv, o1.z*inv, o1.w*inv);
      } else {
        const float* ap = A + (size_t)(n0 + arow) * K + k0 + akseg;
        a0 = *(const float4*)ap; a1 = *(const float4*)(ap + 4);
        if (ASTAGE == 1) {
          const float* p2 = A2 + (size_t)(n0 + arow) * K + k0 + akseg;
          float4 c0 = *(const float4*)p2, c1 = *(const float4*)(p2 + 4);
          a0.x += c0.x; a0.y += c0.y; a0.z += c0.z; a0.w += c0.w;
          a1.x += c1.x; a1.y += c1.y; a1.z += c1.z; a1.w += c1.w;
        } else if (ASTAGE == 2) {
          const float* p2 = A2 + (size_t)(n0 + arow) * K + k0 + akseg;
          float4 c0 = *(const float4*)p2, c1 = *(const float4*)(p2 + 4);
          const float* af = affs + k0 + akseg;
          float4 s1a = *(const float4*)af,         s1b = *(const float4*)(af + 4);
          float4 t1a = *(const float4*)(af + 128), t1b = *(const float4*)(af + 132);
          float4 s2a = *(const float4*)(af + 256), s2b = *(const float4*)(af + 260);
          float4 t2a = *(const float4*)(af + 384), t2b = *(const float4*)(af + 388);
          a0.x = a0.x*s1a.x + t1a.x + c0.x*s2a.x + t2a.x;
          a0.y = a0.y*s1a.y + t1a.y + c0.y*s2a.y + t2a.y;
          a0.z = a0.z*s1a.z + t1a.z + c0.z*s2a.z + t2a.z;
          a0.w = a0.w*s1a.w + t1a.w + c0.w*s2a.w + t2a.w;
          a1.x = a1.x*s1b.x + t1b.x + c1.x*s2b.x + t2b.x;
          a1.y = a1.y*s1b.y + t1b.y + c1.y*s2b.y + t2b.y;
          a1.z = a1.z*s1b.z + t1b.z + c1.z*s2b.z + t2b.z;
          a1.w = a1.w*s1b.w + t1b.w + c1.w*s2b.w + t2b.w;
        }
      }
      u16 t8[8] = {f2b(a0.x), f2b(a0.y), f2b(a0.z), f2b(a0.w),
                   f2b(a1.x), f2b(a1.y), f2b(a1.z), f2b(a1.w)};
      *(uint4*)(Ab + ((arow*128 + akseg*2) ^ ((arow & 7) << 4))) = *(uint4*)t8;
    }
    {  // stage B (already bf16, [m][k])
      const u16* bp = Bt + (size_t)(m0 + bcol) * K + k0 + bkseg;
      uint4 b0 = *(const uint4*)bp;
      uint4 b1 = *(const uint4*)(bp + 8);
      int ba = bcol*128 + bkseg*2;
      int sw = (bcol & 7) << 4;
      *(uint4*)(Bb + (ba ^ sw)) = b0;
      *(uint4*)(Bb + ((ba + 16) ^ sw)) = b1;
    }
    __syncthreads();
    int row = wr*16 + li;
    int colAl = wc*32 + li, colBl = colAl + 16;
    #pragma unroll
    for (int ck = 0; ck < 2; ck++) {
      bf16x8 af = *(const bf16x8*)(Ab + ((row*128 + ck*64 + g*16) ^ ((row & 7) << 4)));
      bf16x8 bf0 = *(const bf16x8*)(Bb + ((colAl*128 + ck*64 + g*16) ^ ((colAl & 7) << 4)));
      bf16x8 bf1 = *(const bf16x8*)(Bb + ((colBl*128 + ck*64 + g*16) ^ ((colBl & 7) << 4)));
      acc0 = __builtin_amdgcn_mfma_f32_16x16x32_bf16(af, bf0, acc0, 0, 0, 0);
      acc1 = __builtin_amdgcn_mfma_f32_16x16x32_bf16(af, bf1, acc1, 0, 0, 0);
    }
    __syncthreads();
  }

  const int colA = m0 + wc*32 + li, colB = colA + 16;
  const int colAl = wc*32 + li, colBl = colAl + 16;
  const int rbase = n0 + wr*16 + 4*g;

  if (EPI == 0) {
    float b0 = bias[colA], b1 = bias[colB];
    #pragma unroll
    for (int r = 0; r < 4; r++) {
      float v0 = acc0[r] + b0, v1 = acc1[r] + b1;
      if (RELU) { v0 = fmaxf(v0, 0.f); v1 = fmaxf(v1, 0.f); }
      C[(size_t)(rbase + r) * M + colA] = v0;
      C[(size_t)(rbase + r) * M + colB] = v1;
    }
  } else if (EPI == 1 || EPI == 3) {
    float b0 = bias[colA], b1 = bias[colB];
    float sA1=0, tA1=0, sA2=0, tA2=0, sB1=0, tB1=0, sB2=0, tB2=0;
    if (EPI == 3) {
      auto mk = [&](int col, float& s1, float& t1, float& s2, float& t2) {
        float m1 = sbase[col]*(1.f/NN), v1 = sbase[128+col]*(1.f/NN) - m1*m1;
        s1 = rsqrtf(v1 + 1e-5f) * pg1[col]; t1 = pb1[col] - m1*s1;
        float m2 = sbase[256+col]*(1.f/NN), v2 = sbase[384+col]*(1.f/NN) - m2*m2;
        s2 = rsqrtf(v2 + 1e-5f) * pg2[col]; t2 = pb2[col] - m2*s2;
      };
      mk(colA, sA1, tA1, sA2, tA2);
      mk(colB, sB1, tB1, sB2, tB2);
    }
    float s0 = 0, q0 = 0, s1 = 0, q1 = 0;
    #pragma unroll
    for (int r = 0; r < 4; r++) {
      int rw2 = rbase + r;
      float v0, v1;
      if (EPI == 1) {
        v0 = acc0[r] + b0 + res[(size_t)rw2 * 128 + colA];
        v1 = acc1[r] + b1 + res[(size_t)rw2 * 128 + colB];
      } else {
        v0 = acc0[r] + b0 + res[(size_t)rw2*128 + colA]*sA1 + tA1
                          + res2[(size_t)rw2*128 + colA]*sA2 + tA2;
        v1 = acc1[r] + b1 + res[(size_t)rw2*128 + colB]*sB1 + tB1
                          + res2[(size_t)rw2*128 + colB]*sB2 + tB2;
      }
      C[(size_t)rw2 * M + colA] = v0;
      C[(size_t)rw2 * M + colB] = v1;
      s0 += v0; q0 += v0*v0; s1 += v1; q1 += v1*v1;
    }
    s0 += __shfl_xor(s0, 16); s0 += __shfl_xor(s0, 32);
    q0 += __shfl_xor(q0, 16); q0 += __shfl_xor(q0, 32);
    s1 += __shfl_xor(s1, 16); s1 += __shfl_xor(s1, 32);
    q1 += __shfl_xor(q1, 16); q1 += __shfl_xor(q1, 32);
    float* sred = (float*)As;   // sum plane [wr*64+col], sq plane [128+wr*64+col]
    if (lane < 16) {
      sred[wr*64 + colAl] = s0;  sred[128 + wr*64 + colAl] = q0;
      sred[wr*64 + colBl] = s1;  sred[128 + wr*64 + colBl] = q1;
    }
    __syncthreads();
    if (tid < 128) {
      int c = tid & 63, isq = tid >> 6;
      float v = sred[isq*128 + c] + sred[isq*128 + 64 + c];
      atomicAdd(&stats[isq*128 + m0 + c], v);
    }
  } else {  // EPI == 4: qkv epilogue
    const float QS = 0.17677669529663687f * 1.4426950408889634f;
    auto doq = [&](int col, f32x4 acc, float bb) {
      if (col < 128) {
        int hd = col >> 5, d = col & 31;
        #pragma unroll
        for (int r = 0; r < 4; r++)
          qb[((size_t)hd*NN + rbase + r)*32 + d] = f2b((acc[r] + bb) * QS);
      } else if (col < 256) {
        int hd = (col - 128) >> 5, d = col & 31;
        #pragma unroll
        for (int r = 0; r < 4; r++)
          kb[((size_t)hd*NN + rbase + r)*32 + d] = f2b(acc[r] + bb);
      } else {
        #pragma unroll
        for (int r = 0; r < 4; r++)
          vt[(size_t)(col - 256)*NN + rbase + r] = f2b(acc[r] + bb);
      }
    };
    doq(colA, acc0, bias[colA]);
    doq(colB, acc1, bias[colB]);
  }
}

// ---- BN3 apply (+relu) -> h; optionally pool instead of writing h
__global__ __launch_bounds__(256) void bn3_k(
    const float* __restrict__ out3, const float* __restrict__ stats,
    const float* __restrict__ gamma, const float* __restrict__ beta,
    float* __restrict__ h, const int* __restrict__ batch,
    float* __restrict__ pooled, int dopool) {
  int idx = blockIdx.x*256 + threadIdx.x;
  int c = idx & 127;
  float mean = stats[c] * (1.f/NN);
  float var  = stats[128+c] * (1.f/NN) - mean*mean;
  float rs = rsqrtf(var + 1e-5f);
  float r = fmaxf((out3[idx] - mean) * rs * gamma[c] + beta[c], 0.f);
  if (dopool) atomicAdd(&pooled[batch[idx >> 7]*HH + c], r);
  else        h[idx] = r;
}

// ---------------- MFMA flash attention, LDS-staged K/V (double-buffered) -----
__global__ __launch_bounds__(256) void mfma_attn_k(
    const u16* __restrict__ qb, const u16* __restrict__ kb,
    const u16* __restrict__ vt, float* __restrict__ opart,
    float* __restrict__ lpart) {
  __shared__ __align__(16) u16 kbuf[2][2048];
  __shared__ __align__(16) u16 vbuf[2][2048];
  __shared__ __align__(16) u16 pbuf[4][1024];

  const int tid = threadIdx.x;
  const int w = tid >> 6, lane = tid & 63;
  const int g = lane >> 4, li = lane & 15;
  const int head = blockIdx.z;
  const int q0 = blockIdx.y * 64 + w * 16;
  const int j0 = blockIdx.x * KLEN;

  const bf16x8 qf = *reinterpret_cast<const bf16x8*>(
      qb + ((size_t)(head*NN) + q0 + li)*32 + g*8);

  const int vd = tid >> 3;
  const int vcs = (tid & 7) ^ (vd & 7);
  const u16* kpan = kb + (size_t)head*NN*32;
  const u16* vrow_g = vt + (size_t)(head*32 + vd)*NN;

  f32x4 oacc0 = {0,0,0,0}, oacc1 = {0,0,0,0};
  const f32x4 zz = {0,0,0,0};
  float lsum = 0.f;
  char* pb = (char*)&pbuf[w][0];
  const int swz = (li & 7) << 4;

  {
    uint4 kv = *(const uint4*)(kpan + (size_t)j0*32 + tid*8);
    uint4 vv = *(const uint4*)(vrow_g + j0 + vcs*8);
    *((uint4*)kbuf[0] + tid) = kv;
    *((uint4*)vbuf[0] + tid) = vv;
  }
  __syncthreads();

  const int NSTEP = KLEN / 64;
  int cur = 0;
  for (int s = 0; s < NSTEP; s++) {
    int jt = j0 + s*64;
    bool pf = (s + 1 < NSTEP);
    uint4 kv = {0,0,0,0}, vv = {0,0,0,0};
    if (pf) {
      kv = *(const uint4*)(kpan + (size_t)(jt + 64)*32 + tid*8);
      vv = *(const uint4*)(vrow_g + jt + 64 + vcs*8);
    }
    f32x4 st[4];
    #pragma unroll
    for (int t = 0; t < 4; t++) {
      bf16x8 kf = *(const bf16x8*)&kbuf[cur][(t*16 + li)*32 + g*8];
      st[t] = __builtin_amdgcn_mfma_f32_16x16x32_bf16(kf, qf, zz, 0, 0, 0);
    }
    #pragma unroll
    for (int t = 0; t < 4; t++) {
      float p0 = exp2f(st[t][0]), p1 = exp2f(st[t][1]);
      float p2 = exp2f(st[t][2]), p3 = exp2f(st[t][3]);
      lsum += p0 + p1 + p2 + p3;
      uint2 wv2;
      wv2.x = pkbf2(p0, p1);
      wv2.y = pkbf2(p2, p3);
      *(uint2*)(pb + ((li*128 + t*32 + g*8) ^ swz)) = wv2;
    }
    #pragma unroll
    for (int c = 0; c < 2; c++) {
      bf16x8 pa = *(const bf16x8*)(pb + ((li*128 + c*64 + g*16) ^ swz));
      int vs = ((c*4 + g) ^ (li & 7)) << 4;
      bf16x8 vb0 = *(const bf16x8*)((char*)vbuf[cur] + li*128 + vs);
      bf16x8 vb1 = *(const bf16x8*)((char*)vbuf[cur] + (16 + li)*128 + vs);
      oacc0 = __builtin_amdgcn_mfma_f32_16x16x32_bf16(pa, vb0, oacc0, 0, 0, 0);
      oacc1 = __builtin_amdgcn_mfma_f32_16x16x32_bf16(pa, vb1, oacc1, 0, 0, 0);
    }
    if (pf) {
      *((uint4*)kbuf[cur ^ 1] + tid) = kv;
      *((uint4*)vbuf[cur ^ 1] + tid) = vv;
    }
    __syncthreads();
    cur ^= 1;
  }
  lsum += __shfl_xor(lsum, 16);
  lsum += __shfl_xor(lsum, 32);

  size_t b = (size_t)(blockIdx.x*4 + head)*NN + q0;
  #pragma unroll
  for (int r = 0; r < 4; r++) {
    size_t ob = (b + 4*g + r)*32;
    opart[ob + li]      = oacc0[r];
    opart[ob + 16 + li] = oacc1[r];
  }
  if (lane < 16) lpart[b + lane] = lsum;
}

// ---------------- fused head MLP: per-graph block ----------------
__global__ __launch_bounds__(128) void head_k(
    const float* __restrict__ pooled,
    const float* __restrict__ Wr1, const float* __restrict__ br1,
    const float* __restrict__ Wr2, const float* __restrict__ br2,
    const float* __restrict__ Wc, const float* __restrict__ bc,
    float* __restrict__ out) {
  __shared__ float bufa[128], bufb[128];
  int g = blockIdx.x, c = threadIdx.x;
  bufa[c] = pooled[g*HH + c];
  __syncthreads();
  float acc = br1[c];
  #pragma unroll 8
  for (int k = 0; k < 128; k++) acc += bufa[k] * Wr1[k*128 + c];
  bufb[c] = fmaxf(acc, 0.f);
  __syncthreads();
  acc = br2[c];
  #pragma unroll 8
  for (int k = 0; k < 128; k++) acc += bufb[k] * Wr2[k*128 + c];
  bufa[c] = fmaxf(acc, 0.f);
  __syncthreads();
  if (c < 10) {
    acc = bc[c];
    #pragma unroll 8
    for (int k = 0; k < 128; k++) acc += bufa[k] * Wc[k*10 + c];
    out[g*10 + c] = acc;
  }
}

extern "C" void kernel_launch(void* const* d_in, const int* in_sizes, int n_in,
                              void* d_out, int out_size, void* d_ws, size_t ws_size,
                              hipStream_t stream) {
  const float* x      = (const float*)d_in[0];
  const float* lap    = (const float*)d_in[1];
  const float* rw     = (const float*)d_in[2];
  const int*   ei     = (const int*)d_in[3];
  const int*   batch  = (const int*)d_in[4];
  const float* Wp     = (const float*)d_in[5];
  const float* bp     = (const float*)d_in[6];
  const float* gin_W1 = (const float*)d_in[7];
  const float* gin_b1 = (const float*)d_in[8];
  const float* gin_W2 = (const float*)d_in[9];
  const float* gin_b2 = (const float*)d_in[10];
  const float* bn1_g  = (const float*)d_in[11];
  const float* bn1_b  = (const float*)d_in[12];
  const float* bn2_g  = (const float*)d_in[13];
  const float* bn2_b  = (const float*)d_in[14];
  const float* bn3_g  = (const float*)d_in[15];
  const float* bn3_b  = (const float*)d_in[16];
  const float* ain_w  = (const float*)d_in[17];
  const float* ain_b  = (const float*)d_in[18];
  const float* aout_w = (const float*)d_in[19];
  const float* aout_b = (const float*)d_in[20];
  const float* mlp_W1 = (const float*)d_in[21];
  const float* mlp_b1 = (const float*)d_in[22];
  const float* mlp_W2 = (const float*)d_in[23];
  const float* mlp_b2 = (const float*)d_in[24];
  const float* Wr1    = (const float*)d_in[25];
  const float* br1    = (const float*)d_in[26];
  const float* Wr2    = (const float*)d_in[27];
  const float* br2    = (const float*)d_in[28];
  const float* Wc     = (const float*)d_in[29];
  const float* bc     = (const float*)d_in[30];
  float* out = (float*)d_out;

  float* w = (float*)d_ws;
  float* h      = w + 0;          // 524288
  float* agg    = w + 524288;     // 524288
  float* gtmp   = w + 1048576;    // 524288
  float* pre1   = w + 1572864;    // 524288
  float* pre2   = w + 2097152;    // 524288
  float* mlph   = w + 2621440;    // 1048576
  float* out3   = w + 3670016;    // 524288
  float* opart  = w + 4194304;    // 4194304
  float* lpart  = w + 8388608;    // 131072
  float* stats  = w + 8519680;    // 1536 (2 layers x 768)   [zero region start]
  float* pooled = w + 8521216;    // 8192
  int*   cnt    = (int*)(w + 8529408);    // 4096             [zero region end]
  int*   rowptr = (int*)(w + 8533504);    // 4104 (incl pad)
  int*   cursor = (int*)(w + 8537608);    // 4096
  int*   elist  = (int*)(w + 8541704);    // 65536
  u16*   wts    = (u16*)(w + 8607240);    // 344064 u16
  u16*   qb     = (u16*)(w + 8779272);
  u16*   kb     = (u16*)(w + 9041416);
  u16*   vt     = (u16*)(w + 9303560);

  u16* wpt = wts;
  u16 *qkvWt[2], *g1t[2], *g2t[2], *aot[2], *m1t[2], *m2t[2];
  {
    int off = 16384;
    for (int l = 0; l < 2; l++) {
      qkvWt[l] = wts + off; off += 384*128;
      g1t[l]   = wts + off; off += 128*128;
      g2t[l]   = wts + off; off += 128*128;
      aot[l]   = wts + off; off += 128*128;
      m1t[l]   = wts + off; off += 256*128;
      m2t[l]   = wts + off; off += 128*256;
    }
  }
  TPack tp;
  {
    int ti = 0, toff = 0;
    auto addm = [&](const float* s, int Ks, int Kd, int Md) {
      tp.d[ti].src = s; tp.d[ti].Ks = Ks; tp.d[ti].K = Kd; tp.d[ti].M = Md;
      tp.d[ti].off = toff; toff += Kd * Md; ti++;
    };
    addm(Wp, 88, 128, 128);
    for (int l = 0; l < 2; l++) {
      addm(ain_w + l*HH*384, 128, 128, 384);
      addm(gin_W1 + l*HH*HH, 128, 128, 128);
      addm(gin_W2 + l*HH*HH, 128, 128, 128);
      addm(aout_w + l*HH*HH, 128, 128, 128);
      addm(mlp_W1 + l*HH*256, 128, 128, 256);
      addm(mlp_W2 + l*256*HH, 256, 256, 128);
    }
  }

  // one memset: stats(1536) + pooled(8192) + cnt(4096) = 13824 floats contiguous
  hipMemsetAsync(stats, 0, 13824*sizeof(float), stream);
  transpose_all_k<<<1344, 256, 0, stream>>>(tp, wts);
  count_k<<<EE/256, 256, 0, stream>>>(ei, cnt);
  scan_k<<<1, 256, 0, stream>>>(cnt, rowptr, cursor);
  scatter_k<<<EE/256, 256, 0, stream>>>(ei, cursor, elist);
  // input projection with inline [x|lap|rw|0] concat staging
  mgemm_k<4,0,0><<<dim3(128,2), 256, 0, stream>>>(
      x, lap, rw, wpt, bp, h,
      nullptr, nullptr, nullptr, nullptr, nullptr, nullptr, nullptr, nullptr,
      nullptr, nullptr, nullptr, nullptr, nullptr, 128, 128);

  for (int l = 0; l < 2; l++) {
    float* st1 = stats + l*768;
    float* st2 = st1 + 256;
    float* st3 = st1 + 512;

    aggcsr_k<<<NN/2, 256, 0, stream>>>(rowptr, elist, h, agg);

    // ---- attention branch ----
    mgemm_k<0,4,0><<<dim3(128,6), 256, 0, stream>>>(
        h, nullptr, nullptr, qkvWt[l], ain_b + l*384, nullptr,
        nullptr, nullptr, nullptr, nullptr, nullptr, nullptr, nullptr, nullptr,
        nullptr, nullptr, qb, kb, vt, 128, 384);
    mfma_attn_k<<<dim3(KSPLIT,64,4), 256, 0, stream>>>(qb, kb, vt, opart, lpart);

    // ---- GIN branch ----
    mgemm_k<1,0,1><<<dim3(128,2), 256, 0, stream>>>(
        h, agg, nullptr, g1t[l], gin_b1 + l*HH, gtmp,
        nullptr, nullptr, nullptr, nullptr, nullptr, nullptr, nullptr, nullptr,
        nullptr, nullptr, nullptr, nullptr, nullptr, 128, 128);
    mgemm_k<0,1,0><<<dim3(128,2), 256, 0, stream>>>(
        gtmp, nullptr, nullptr, g2t[l], gin_b2 + l*HH, pre1,
        h, nullptr, st1, nullptr, nullptr, nullptr, nullptr, nullptr,
        nullptr, nullptr, nullptr, nullptr, nullptr, 128, 128);
    // attn-out GEMM with inline KSPLIT merge in A-staging
    mgemm_k<3,1,0><<<dim3(128,2), 256, 0, stream>>>(
        nullptr, nullptr, nullptr, aot[l], aout_b + l*HH, pre2,
        h, nullptr, st2, nullptr, nullptr, nullptr, nullptr, nullptr,
        opart, lpart, nullptr, nullptr, nullptr, 128, 128);

    // ---- combine + FFN (BN affines computed inline from stats) ----
    mgemm_k<2,0,1><<<dim3(128,4), 256, 0, stream>>>(
        pre1, pre2, nullptr, m1t[l], mlp_b1 + l*256, mlph,
        nullptr, nullptr, nullptr, st1,
        bn1_g + l*HH, bn1_b + l*HH, bn2_g + l*HH, bn2_b + l*HH,
        nullptr, nullptr, nullptr, nullptr, nullptr, 128, 256);
    mgemm_k<0,3,0><<<dim3(128,2), 256, 0, stream>>>(
        mlph, nullptr, nullptr, m2t[l], mlp_b2 + l*HH, out3,
        pre1, pre2, st3, st1,
        bn1_g + l*HH, bn1_b + l*HH, bn2_g + l*HH, bn2_b + l*HH,
        nullptr, nullptr, nullptr, nullptr, nullptr, 256, 128);
    bn3_k<<<NN*HH/256, 256, 0, stream>>>(out3, st3, bn3_g + l*HH, bn3_b + l*HH,
                                         h, batch, pooled, l == 1);
  }

  head_k<<<GG, 128, 0, stream>>>(pooled, Wr1, br1, Wr2, br2, Wc, bc, out);
}